// Round 3
// baseline (1044.994 us; speedup 1.0000x reference)
//
#include <hip/hip_runtime.h>

typedef float f32x4 __attribute__((ext_vector_type(4)));
typedef __bf16 bf16x8 __attribute__((ext_vector_type(8)));

#define MU (1.0f / 1024.0f)

__device__ __forceinline__ float bf2f(ushort u) {
  union { uint i; float f; } v; v.i = ((uint)u) << 16; return v.f;
}
__device__ __forceinline__ ushort f2bf(float f) {
  union { float f; uint i; } v; v.f = f;
  uint r = v.i + 0x7fffu + ((v.i >> 16) & 1u);  // RNE
  return (ushort)(r >> 16);
}

// ---------------- LayerNorm: x[4096][769] f32 -> xnb[4096][800] bf16 (zero-pad K) ---
__global__ __launch_bounds__(256) void ln_k(const float* __restrict__ x,
                                            const float* __restrict__ w,
                                            const float* __restrict__ b,
                                            ushort* __restrict__ xnb) {
  const int row = blockIdx.x;
  const int tid = threadIdx.x;
  const float* xr = x + (size_t)row * 769;
  float s = 0.f, ss = 0.f;
  for (int c = tid; c < 769; c += 256) { float v = xr[c]; s += v; ss += v * v; }
  for (int o = 32; o; o >>= 1) { s += __shfl_down(s, o); ss += __shfl_down(ss, o); }
  __shared__ float rs[4], rss[4];
  if ((tid & 63) == 0) { rs[tid >> 6] = s; rss[tid >> 6] = ss; }
  __syncthreads();
  s  = rs[0] + rs[1] + rs[2] + rs[3];
  ss = rss[0] + rss[1] + rss[2] + rss[3];
  const float mean = s * (1.0f / 769.0f);
  const float var  = ss * (1.0f / 769.0f) - mean * mean;
  const float rstd = rsqrtf(var + 1e-5f);
  ushort* orow = xnb + (size_t)row * 800;
  for (int c = tid; c < 800; c += 256) {
    float o = 0.f;
    if (c < 769) o = (xr[c] - mean) * rstd * w[c] + b[c];
    orow[c] = f2bf(o);
  }
}

// ---------------- transpose W[K][N] f32 -> Wt[N][Kp] bf16 (zero-pad K..Kp) ----------
__global__ __launch_bounds__(256) void tr_k(const float* __restrict__ W,
                                            ushort* __restrict__ Wt,
                                            int K, int N, int Kp) {
  __shared__ float ls[32][33];
  const int n0 = blockIdx.x * 32, k0 = blockIdx.y * 32;
  const int c = threadIdx.x & 31, r = threadIdx.x >> 5;  // r in 0..7
  for (int rr = 0; rr < 32; rr += 8) {
    int k = k0 + r + rr;
    ls[r + rr][c] = (k < K) ? W[(size_t)k * N + n0 + c] : 0.f;
  }
  __syncthreads();
  for (int rr = 0; rr < 32; rr += 8) {
    int n = n0 + r + rr;
    if (k0 + c < Kp) Wt[(size_t)n * Kp + k0 + c] = f2bf(ls[c][r + rr]);
  }
}

// ---------------- shared GEMM core: C[64x64] = A[M][K] * Bt[N][K]^T, bf16 MFMA ------
#define GEMM_PROLOG() \
  __shared__ __align__(16) ushort lsA[64 * 40]; \
  __shared__ __align__(16) ushort lsB[64 * 40]; \
  const int tid = threadIdx.x; \
  const int lane = tid & 63; \
  const int wid = tid >> 6; \
  const int wr = wid >> 1, wc = wid & 1; \
  const int l15 = lane & 15, l4 = lane >> 4; \
  const int srow = tid >> 2, scol = (tid & 3) << 3; \
  f32x4 acc00 = {0.f, 0.f, 0.f, 0.f}; \
  f32x4 acc01 = acc00, acc10 = acc00, acc11 = acc00;

#define GEMM_LOOP(Aptr, Btptr, lda, ldb, kdim) \
  { const size_t aoff0 = (size_t)(arow0 + srow) * (lda) + scol; \
    const size_t boff0 = (size_t)(brow0 + srow) * (ldb) + scol; \
    for (int k0 = 0; k0 < (kdim); k0 += 32) { \
      uint4 av = *(const uint4*)((Aptr) + aoff0 + k0); \
      uint4 bv = *(const uint4*)((Btptr) + boff0 + k0); \
      __syncthreads(); \
      *(uint4*)(lsA + srow * 40 + scol) = av; \
      *(uint4*)(lsB + srow * 40 + scol) = bv; \
      __syncthreads(); \
      bf16x8 af0 = *(const bf16x8*)(lsA + (wr * 32 + l15) * 40 + l4 * 8); \
      bf16x8 af1 = *(const bf16x8*)(lsA + (wr * 32 + 16 + l15) * 40 + l4 * 8); \
      bf16x8 bq0 = *(const bf16x8*)(lsB + (wc * 32 + l15) * 40 + l4 * 8); \
      bf16x8 bq1 = *(const bf16x8*)(lsB + (wc * 32 + 16 + l15) * 40 + l4 * 8); \
      acc00 = __builtin_amdgcn_mfma_f32_16x16x32_bf16(af0, bq0, acc00, 0, 0, 0); \
      acc01 = __builtin_amdgcn_mfma_f32_16x16x32_bf16(af0, bq1, acc01, 0, 0, 0); \
      acc10 = __builtin_amdgcn_mfma_f32_16x16x32_bf16(af1, bq0, acc10, 0, 0, 0); \
      acc11 = __builtin_amdgcn_mfma_f32_16x16x32_bf16(af1, bq1, acc11, 0, 0, 0); \
    } }

#define EPI_ONE(ACC, FM, FN, ...) \
  { _Pragma("unroll") for (int r = 0; r < 4; ++r) { \
      int gr = arow0 + wr * 32 + (FM) * 16 + l4 * 4 + r; \
      int gc = brow0 + wc * 32 + (FN) * 16 + l15; \
      float val = ACC[r]; \
      __VA_ARGS__; \
  } }
#define GEMM_EPILOG(...) \
  EPI_ONE(acc00, 0, 0, __VA_ARGS__) EPI_ONE(acc01, 0, 1, __VA_ARGS__) \
  EPI_ONE(acc10, 1, 0, __VA_ARGS__) EPI_ONE(acc11, 1, 1, __VA_ARGS__)

// ---------------- QKV GEMM: xnb[4096][800] * WaT[2304][800]^T, scatter q/k/Vt -------
__global__ __launch_bounds__(256) void gemm_qkv_k(
    const ushort* __restrict__ xnb, const ushort* __restrict__ WaT,
    const float* __restrict__ b_attn,
    ushort* __restrict__ qb, ushort* __restrict__ kb, float* __restrict__ Vt) {
  const int arow0 = blockIdx.y * 64;
  const int brow0 = blockIdx.x * 64;
  GEMM_PROLOG();
  GEMM_LOOP(xnb, WaT, 800, 800, 800);
  GEMM_EPILOG({
    val += b_attn[gc];
    int sect = gc / 768;
    int e = gc - sect * 768;
    int h = e >> 6;
    int d = e & 63;
    int bb = gr >> 10;
    int t = gr & 1023;
    size_t bh = (size_t)(bb * 12 + h);
    if (sect == 0)      qb[(bh << 16) + ((size_t)t << 6) + d] = f2bf(val * 0.125f);
    else if (sect == 1) kb[(bh << 16) + ((size_t)t << 6) + d] = f2bf(val);
    else                Vt[(bh << 16) + ((size_t)d << 10) + t] = val;
  });
}

// ---------------- S = q k^T per (b,h): store bf16 logits (lower triangle tiles) -----
__global__ __launch_bounds__(256) void gemm_s_k(
    const ushort* __restrict__ qb, const ushort* __restrict__ kb,
    ushort* __restrict__ SK) {
  const int kt = blockIdx.x, qt = blockIdx.y, bh = blockIdx.z;
  if (kt > qt) return;  // strictly above diagonal: never read
  const int arow0 = qt * 64;
  const int brow0 = kt * 64;
  const ushort* A = qb + ((size_t)bh << 16);
  const ushort* B = kb + ((size_t)bh << 16);
  ushort* S = SK + ((size_t)bh << 20);
  GEMM_PROLOG();
  GEMM_LOOP(A, B, 64, 64, 64);
  GEMM_EPILOG({ S[((size_t)gr << 10) + gc] = f2bf(val); });
}

// ---- row softmax p, then store D = 1-exp(-p) in place (0 above diag; lower-tri) ----
__global__ __launch_bounds__(256) void kmat_k(ushort* __restrict__ SK) {
  const int bid = blockIdx.x;          // bh*1024 + i
  const int i = bid & 1023;
  ushort* row = SK + ((size_t)bid << 10);
  __shared__ float sr[1024];
  __shared__ float red[4];
  const int tid = threadIdx.x, lane = tid & 63, widx = tid >> 6;
  for (int c = tid; c <= i; c += 256) sr[c] = bf2f(row[c]);
  __syncthreads();
  float m = -1e30f;
  for (int c = tid; c <= i; c += 256) m = fmaxf(m, sr[c]);
  for (int o = 32; o; o >>= 1) m = fmaxf(m, __shfl_down(m, o));
  if (lane == 0) red[widx] = m;
  __syncthreads();
  m = fmaxf(fmaxf(red[0], red[1]), fmaxf(red[2], red[3]));
  __syncthreads();
  float s = 0.f;
  for (int c = tid; c <= i; c += 256) s += expf(sr[c] - m);
  for (int o = 32; o; o >>= 1) s += __shfl_down(s, o);
  if (lane == 0) red[widx] = s;
  __syncthreads();
  const float inv = 1.0f / (red[0] + red[1] + red[2] + red[3]);
  for (int c = tid; c < 1024; c += 256) {
    float D = 0.0f;
    if (c <= i) D = -expm1f(-expf(sr[c] - m) * inv);
    row[c] = f2bf(D);
  }
}

// ---------------- Sinkhorn: u = mu/(sv - Dv), v = mu/(su - D^T u) -------------------
__global__ __launch_bounds__(256) void init_v_k(float* __restrict__ vv) {
  int id = blockIdx.x * 256 + threadIdx.x;
  if (id < 48 * 1024) vv[id] = 1.0f;
}

__device__ __forceinline__ float dot8(uint4 dv, const float* __restrict__ vp) {
  float s;
  s  = bf2f((ushort)(dv.x)) * vp[0];
  s += bf2f((ushort)(dv.x >> 16)) * vp[1];
  s += bf2f((ushort)(dv.y)) * vp[2];
  s += bf2f((ushort)(dv.y >> 16)) * vp[3];
  s += bf2f((ushort)(dv.z)) * vp[4];
  s += bf2f((ushort)(dv.z >> 16)) * vp[5];
  s += bf2f((ushort)(dv.w)) * vp[6];
  s += bf2f((ushort)(dv.w >> 16)) * vp[7];
  return s;
}

__global__ __launch_bounds__(256) void srow_k(const ushort* __restrict__ SK,
                                              const float* __restrict__ vv,
                                              float* __restrict__ u) {
  const int bid = blockIdx.x;           // bh*1024 + i
  const int i = bid & 1023;
  const int bh = bid >> 10;
  const int tid = threadIdx.x;
  const ushort* row = SK + ((size_t)bid << 10);
  const float* vb = vv + (bh << 10);
  float sv = 0.f;
  for (int c = tid; c < 1024; c += 256) sv += vb[c];
  float a = 0.f;
  const int nc = (i + 1) >> 3;          // full 8-elem chunks in [0, i]
  for (int cc = tid; cc < nc; cc += 256)
    a += dot8(*(const uint4*)(row + cc * 8), vb + cc * 8);
  if (tid == 0)
    for (int c = nc * 8; c <= i; ++c) a += bf2f(row[c]) * vb[c];
  for (int o = 32; o; o >>= 1) { a += __shfl_down(a, o); sv += __shfl_down(sv, o); }
  __shared__ float r1[4], r2[4];
  if ((tid & 63) == 0) { r1[tid >> 6] = a; r2[tid >> 6] = sv; }
  __syncthreads();
  if (tid == 0)
    u[bid] = MU / ((r2[0] + r2[1] + r2[2] + r2[3]) - (r1[0] + r1[1] + r1[2] + r1[3]));
}

__global__ __launch_bounds__(256) void scol_k(const ushort* __restrict__ SK,
                                              const float* __restrict__ u,
                                              float* __restrict__ vv) {
  const int chunk = blockIdx.x, bh = blockIdx.y;
  const int tid = threadIdx.x, lane = tid & 63, q = tid >> 6;
  const int j = (chunk << 6) + lane;
  const ushort* base = SK + ((size_t)bh << 20);
  const float* ub = u + (bh << 10);
  float su = 0.f;
  for (int ii = tid; ii < 1024; ii += 256) su += ub[ii];
  const int istart = chunk << 6;        // rows < istart have D=0 in these columns
  const int per = (1024 - istart) >> 2;
  const int i0 = istart + q * per;
  float a = 0.f;
  for (int i = i0; i < i0 + per; ++i)
    a += bf2f(base[((size_t)i << 10) + j]) * ub[i];
  for (int o = 32; o; o >>= 1) su += __shfl_down(su, o);
  __shared__ float ra[4][64];
  __shared__ float rs[4];
  ra[q][lane] = a;
  if (lane == 0) rs[q] = su;
  __syncthreads();
  if (tid < 64) {
    float sut = rs[0] + rs[1] + rs[2] + rs[3];
    float at = ra[0][tid] + ra[1][tid] + ra[2][tid] + ra[3][tid];
    vv[(bh << 10) + istart + tid] = MU / (sut - at);
  }
}

// ---------------- V' = v ⊙ V (bf16, d-major) + Wd[bh][d] = sum_t V'[t][d] -----------
__global__ __launch_bounds__(256) void vprep_k(const float* __restrict__ Vt,
                                               const float* __restrict__ vv,
                                               ushort* __restrict__ Vpt,
                                               float* __restrict__ Wd) {
  const int bd = blockIdx.x;            // bh*64 + d
  const int bh = bd >> 6;
  const int tid = threadIdx.x;
  const float* src = Vt + ((size_t)bd << 10);
  const float* vb = vv + (bh << 10);
  ushort* dst = Vpt + ((size_t)bd << 10);
  float s = 0.f;
  for (int t = tid; t < 1024; t += 256) {
    float p = src[t] * vb[t];
    s += p;
    dst[t] = f2bf(p);
  }
  for (int o = 32; o; o >>= 1) s += __shfl_down(s, o);
  __shared__ float red[4];
  if ((tid & 63) == 0) red[tid >> 6] = s;
  __syncthreads();
  if (tid == 0) Wd[bd] = red[0] + red[1] + red[2] + red[3];
}

// ------- y = 1024*u ⊙ (Wd - D @ V'), write [B][T][H*64+d] bf16 (triangular K) -------
__global__ __launch_bounds__(256) void gemm_pv_k(
    const ushort* __restrict__ SK, const ushort* __restrict__ Vpt,
    const float* __restrict__ u, const float* __restrict__ Wd,
    ushort* __restrict__ yb) {
  const int qt = blockIdx.y, bh = blockIdx.z;
  const int arow0 = qt * 64;
  const int brow0 = 0;
  const int kdim = (qt + 1) << 6;       // D rows in this tile end at col kdim-1
  const ushort* A = SK + ((size_t)bh << 20);
  const ushort* B = Vpt + ((size_t)bh << 16);
  GEMM_PROLOG();
  GEMM_LOOP(A, B, 1024, 1024, kdim);
  const int bb = bh / 12, h = bh - bb * 12;
  GEMM_EPILOG({
    float yv = (Wd[(bh << 6) + gc] - val) * u[(bh << 10) + gr] * 1024.0f;
    yb[((size_t)((bb << 10) + gr)) * 768 + (h << 6) + gc] = f2bf(yv);
  });
}

// ---------------- out = y @ Wp + b_proj (fp32 out) ----------------------------------
__global__ __launch_bounds__(256) void gemm_proj_k(
    const ushort* __restrict__ yb, const ushort* __restrict__ WpT,
    const float* __restrict__ b_proj, float* __restrict__ out) {
  const int arow0 = blockIdx.y * 64;
  const int brow0 = blockIdx.x * 64;
  GEMM_PROLOG();
  GEMM_LOOP(yb, WpT, 768, 768, 768);
  GEMM_EPILOG({ out[(size_t)gr * 768 + gc] = val + b_proj[gc]; });
}

// ------------------------------------------------------------------------------------
extern "C" void kernel_launch(void* const* d_in, const int* in_sizes, int n_in,
                              void* d_out, int out_size, void* d_ws, size_t ws_size,
                              hipStream_t stream) {
  const float* x      = (const float*)d_in[0];
  const float* ln_w   = (const float*)d_in[1];
  const float* ln_b   = (const float*)d_in[2];
  const float* W_attn = (const float*)d_in[3];
  const float* b_attn = (const float*)d_in[4];
  const float* W_proj = (const float*)d_in[5];
  const float* b_proj = (const float*)d_in[6];
  float* out = (float*)d_out;
  char* ws = (char*)d_ws;

  // ws layout (bytes); total ~150.3 MB
  ushort* xnb = (ushort*)(ws + 0);            // 4096*800 bf16
  ushort* WaT = (ushort*)(ws + 6553600);      // 2304*800 bf16
  ushort* WpT = (ushort*)(ws + 10240000);     // 768*768 bf16
  ushort* qb  = (ushort*)(ws + 11419648);     // 48*1024*64 bf16 (q/8)
  ushort* kb  = (ushort*)(ws + 17711104);     // 48*1024*64 bf16
  float*  Vt  = (float*) (ws + 24002560);     // 48*64*1024 f32 (d-major)
  ushort* SK  = (ushort*)(ws + 36585472);     // 48*1024*1024 bf16 (S, then D)
  ushort* Vpt = (ushort*)(ws + 137248768);    // 48*64*1024 bf16
  ushort* yb  = (ushort*)(ws + 143540224);    // 4096*768 bf16
  float*  u   = (float*) (ws + 149831680);    // 48*1024 f32
  float*  vv  = (float*) (ws + 150028288);    // 48*1024 f32
  float*  Wd  = (float*) (ws + 150224896);    // 48*64 f32

  hipLaunchKernelGGL(ln_k, dim3(4096), dim3(256), 0, stream, x, ln_w, ln_b, xnb);
  hipLaunchKernelGGL(tr_k, dim3(72, 25), dim3(256), 0, stream, W_attn, WaT, 769, 2304, 800);
  hipLaunchKernelGGL(tr_k, dim3(24, 24), dim3(256), 0, stream, W_proj, WpT, 768, 768, 768);
  hipLaunchKernelGGL(gemm_qkv_k, dim3(36, 64), dim3(256), 0, stream,
                     xnb, WaT, b_attn, qb, kb, Vt);
  hipLaunchKernelGGL(gemm_s_k, dim3(16, 16, 48), dim3(256), 0, stream, qb, kb, SK);
  hipLaunchKernelGGL(kmat_k, dim3(49152), dim3(256), 0, stream, SK);
  hipLaunchKernelGGL(init_v_k, dim3(192), dim3(256), 0, stream, vv);
  for (int it = 0; it < 6; ++it) {
    hipLaunchKernelGGL(srow_k, dim3(49152), dim3(256), 0, stream, SK, vv, u);
    hipLaunchKernelGGL(scol_k, dim3(16, 48), dim3(256), 0, stream, SK, u, vv);
  }
  hipLaunchKernelGGL(vprep_k, dim3(3072), dim3(256), 0, stream, Vt, vv, Vpt, Wd);
  hipLaunchKernelGGL(gemm_pv_k, dim3(1, 16, 48), dim3(256), 0, stream, SK, Vpt, u, Wd, yb);
  hipLaunchKernelGGL(gemm_proj_k, dim3(12, 64), dim3(256), 0, stream, yb, WpT, b_proj, out);
}

// Round 4
// 345.392 us; speedup vs baseline: 3.0255x; 3.0255x over previous
//
#include <hip/hip_runtime.h>

typedef float f32x4 __attribute__((ext_vector_type(4)));
typedef __bf16 bf16x8 __attribute__((ext_vector_type(8)));

#define MU (1.0f / 1024.0f)

__device__ __forceinline__ float bf2f(ushort u) {
  union { uint i; float f; } v; v.i = ((uint)u) << 16; return v.f;
}
__device__ __forceinline__ ushort f2bf(float f) {
  union { float f; uint i; } v; v.f = f;
  uint r = v.i + 0x7fffu + ((v.i >> 16) & 1u);  // RNE
  return (ushort)(r >> 16);
}
__device__ __forceinline__ void up8(uint4 v, float* o) {
  o[0] = bf2f((ushort)v.x); o[1] = bf2f((ushort)(v.x >> 16));
  o[2] = bf2f((ushort)v.y); o[3] = bf2f((ushort)(v.y >> 16));
  o[4] = bf2f((ushort)v.z); o[5] = bf2f((ushort)(v.z >> 16));
  o[6] = bf2f((ushort)v.w); o[7] = bf2f((ushort)(v.w >> 16));
}
__device__ __forceinline__ uint4 pk8(const float* f) {
  uint4 r;
  r.x = (uint)f2bf(f[0]) | ((uint)f2bf(f[1]) << 16);
  r.y = (uint)f2bf(f[2]) | ((uint)f2bf(f[3]) << 16);
  r.z = (uint)f2bf(f[4]) | ((uint)f2bf(f[5]) << 16);
  r.w = (uint)f2bf(f[6]) | ((uint)f2bf(f[7]) << 16);
  return r;
}

// ---------------- LayerNorm: x[4096][769] f32 -> xnb[4096][800] bf16 (zero-pad K) ---
__global__ __launch_bounds__(256) void ln_k(const float* __restrict__ x,
                                            const float* __restrict__ w,
                                            const float* __restrict__ b,
                                            ushort* __restrict__ xnb) {
  const int row = blockIdx.x;
  const int tid = threadIdx.x;
  const float* xr = x + (size_t)row * 769;
  float s = 0.f, ss = 0.f;
  for (int c = tid; c < 769; c += 256) { float v = xr[c]; s += v; ss += v * v; }
  for (int o = 32; o; o >>= 1) { s += __shfl_down(s, o); ss += __shfl_down(ss, o); }
  __shared__ float rs[4], rss[4];
  if ((tid & 63) == 0) { rs[tid >> 6] = s; rss[tid >> 6] = ss; }
  __syncthreads();
  s  = rs[0] + rs[1] + rs[2] + rs[3];
  ss = rss[0] + rss[1] + rss[2] + rss[3];
  const float mean = s * (1.0f / 769.0f);
  const float var  = ss * (1.0f / 769.0f) - mean * mean;
  const float rstd = rsqrtf(var + 1e-5f);
  ushort* orow = xnb + (size_t)row * 800;
  for (int c = tid; c < 800; c += 256) {
    float o = 0.f;
    if (c < 769) o = (xr[c] - mean) * rstd * w[c] + b[c];
    orow[c] = f2bf(o);
  }
}

// ---------------- transpose W[K][N] f32 -> Wt[N][Kp] bf16 (zero-pad K..Kp) ----------
__global__ __launch_bounds__(256) void tr_k(const float* __restrict__ W,
                                            ushort* __restrict__ Wt,
                                            int K, int N, int Kp) {
  __shared__ float ls[32][33];
  const int n0 = blockIdx.x * 32, k0 = blockIdx.y * 32;
  const int c = threadIdx.x & 31, r = threadIdx.x >> 5;  // r in 0..7
  for (int rr = 0; rr < 32; rr += 8) {
    int k = k0 + r + rr;
    ls[r + rr][c] = (k < K) ? W[(size_t)k * N + n0 + c] : 0.f;
  }
  __syncthreads();
  for (int rr = 0; rr < 32; rr += 8) {
    int n = n0 + r + rr;
    if (k0 + c < Kp) Wt[(size_t)n * Kp + k0 + c] = f2bf(ls[c][r + rr]);
  }
}

// ---------------- shared GEMM core: C[64x64] = A[M][K] * Bt[N][K]^T, bf16 MFMA ------
#define GEMM_PROLOG() \
  __shared__ __align__(16) ushort lsA[64 * 40]; \
  __shared__ __align__(16) ushort lsB[64 * 40]; \
  const int tid = threadIdx.x; \
  const int lane = tid & 63; \
  const int wid = tid >> 6; \
  const int wr = wid >> 1, wc = wid & 1; \
  const int l15 = lane & 15, l4 = lane >> 4; \
  const int srow = tid >> 2, scol = (tid & 3) << 3; \
  f32x4 acc00 = {0.f, 0.f, 0.f, 0.f}; \
  f32x4 acc01 = acc00, acc10 = acc00, acc11 = acc00;

#define GEMM_LOOP(Aptr, Btptr, lda, ldb, kdim) \
  { const size_t aoff0 = (size_t)(arow0 + srow) * (lda) + scol; \
    const size_t boff0 = (size_t)(brow0 + srow) * (ldb) + scol; \
    for (int k0 = 0; k0 < (kdim); k0 += 32) { \
      uint4 av = *(const uint4*)((Aptr) + aoff0 + k0); \
      uint4 bv = *(const uint4*)((Btptr) + boff0 + k0); \
      __syncthreads(); \
      *(uint4*)(lsA + srow * 40 + scol) = av; \
      *(uint4*)(lsB + srow * 40 + scol) = bv; \
      __syncthreads(); \
      bf16x8 af0 = *(const bf16x8*)(lsA + (wr * 32 + l15) * 40 + l4 * 8); \
      bf16x8 af1 = *(const bf16x8*)(lsA + (wr * 32 + 16 + l15) * 40 + l4 * 8); \
      bf16x8 bq0 = *(const bf16x8*)(lsB + (wc * 32 + l15) * 40 + l4 * 8); \
      bf16x8 bq1 = *(const bf16x8*)(lsB + (wc * 32 + 16 + l15) * 40 + l4 * 8); \
      acc00 = __builtin_amdgcn_mfma_f32_16x16x32_bf16(af0, bq0, acc00, 0, 0, 0); \
      acc01 = __builtin_amdgcn_mfma_f32_16x16x32_bf16(af0, bq1, acc01, 0, 0, 0); \
      acc10 = __builtin_amdgcn_mfma_f32_16x16x32_bf16(af1, bq0, acc10, 0, 0, 0); \
      acc11 = __builtin_amdgcn_mfma_f32_16x16x32_bf16(af1, bq1, acc11, 0, 0, 0); \
    } }

#define EPI_ONE(ACC, FM, FN, ...) \
  { _Pragma("unroll") for (int r = 0; r < 4; ++r) { \
      int gr = arow0 + wr * 32 + (FM) * 16 + l4 * 4 + r; \
      int gc = brow0 + wc * 32 + (FN) * 16 + l15; \
      float val = ACC[r]; \
      __VA_ARGS__; \
  } }
#define GEMM_EPILOG(...) \
  EPI_ONE(acc00, 0, 0, __VA_ARGS__) EPI_ONE(acc01, 0, 1, __VA_ARGS__) \
  EPI_ONE(acc10, 1, 0, __VA_ARGS__) EPI_ONE(acc11, 1, 1, __VA_ARGS__)

// ---------------- QKV GEMM: xnb[4096][800] * WaT[2304][800]^T, scatter q/k/Vt -------
__global__ __launch_bounds__(256) void gemm_qkv_k(
    const ushort* __restrict__ xnb, const ushort* __restrict__ WaT,
    const float* __restrict__ b_attn,
    ushort* __restrict__ qb, ushort* __restrict__ kb, float* __restrict__ Vt) {
  const int arow0 = blockIdx.y * 64;
  const int brow0 = blockIdx.x * 64;
  GEMM_PROLOG();
  GEMM_LOOP(xnb, WaT, 800, 800, 800);
  GEMM_EPILOG({
    val += b_attn[gc];
    int sect = gc / 768;
    int e = gc - sect * 768;
    int h = e >> 6;
    int d = e & 63;
    int bb = gr >> 10;
    int t = gr & 1023;
    size_t bh = (size_t)(bb * 12 + h);
    if (sect == 0)      qb[(bh << 16) + ((size_t)t << 6) + d] = f2bf(val * 0.125f);
    else if (sect == 1) kb[(bh << 16) + ((size_t)t << 6) + d] = f2bf(val);
    else                Vt[(bh << 16) + ((size_t)d << 10) + t] = val;
  });
}

// ---------------- S = q k^T per (b,h): store bf16 logits (lower triangle tiles) -----
__global__ __launch_bounds__(256) void gemm_s_k(
    const ushort* __restrict__ qb, const ushort* __restrict__ kb,
    ushort* __restrict__ SK) {
  const int kt = blockIdx.x, qt = blockIdx.y, bh = blockIdx.z;
  if (kt > qt) return;  // strictly above diagonal: never read
  const int arow0 = qt * 64;
  const int brow0 = kt * 64;
  const ushort* A = qb + ((size_t)bh << 16);
  const ushort* B = kb + ((size_t)bh << 16);
  ushort* S = SK + ((size_t)bh << 20);
  GEMM_PROLOG();
  GEMM_LOOP(A, B, 64, 64, 64);
  GEMM_EPILOG({ S[((size_t)gr << 10) + gc] = f2bf(val); });
}

// ---- row softmax p, then D = 1-exp(-p) in place (0 above diag). Wave per row. ------
__global__ __launch_bounds__(256) void kmat_k(ushort* __restrict__ SK) {
  const int tid = threadIdx.x, lane = tid & 63, w = tid >> 6;
  const int rg = blockIdx.x * 4 + w;        // global row index 0..49151
  const int i = rg & 1023;
  ushort* row = SK + ((size_t)rg << 10);
  const int nc8 = i >> 3;                   // last valid 8-chunk
  const int cA = lane, cB = lane + 64;
  uint4 z4 = make_uint4(0, 0, 0, 0);
  uint4 da = (cA <= nc8) ? *(const uint4*)(row + 8 * cA) : z4;
  uint4 db = (cB <= nc8) ? *(const uint4*)(row + 512 + 8 * cB - 512) : z4;
  float xa[8], xb[8];
  up8(da, xa); up8(db, xb);
  float m = -1e30f;
#pragma unroll
  for (int e = 0; e < 8; ++e) {
    if (8 * cA + e <= i) m = fmaxf(m, xa[e]);
    if (8 * cB + e <= i) m = fmaxf(m, xb[e]);
  }
#pragma unroll
  for (int o = 1; o < 64; o <<= 1) m = fmaxf(m, __shfl_xor(m, o));
  float pa[8], pb[8];
  float s = 0.f;
#pragma unroll
  for (int e = 0; e < 8; ++e) {
    pa[e] = (8 * cA + e <= i) ? __expf(xa[e] - m) : 0.f;
    pb[e] = (8 * cB + e <= i) ? __expf(xb[e] - m) : 0.f;
    s += pa[e] + pb[e];
  }
#pragma unroll
  for (int o = 1; o < 64; o <<= 1) s += __shfl_xor(s, o);
  const float inv = 1.0f / s;
  float Da[8], Db[8];
#pragma unroll
  for (int e = 0; e < 8; ++e) {
    Da[e] = (8 * cA + e <= i) ? (1.0f - __expf(-pa[e] * inv)) : 0.f;
    Db[e] = (8 * cB + e <= i) ? (1.0f - __expf(-pb[e] * inv)) : 0.f;
  }
  *(uint4*)(row + 8 * cA) = pk8(Da);
  *(uint4*)(row + 8 * cB) = pk8(Db);
}

// ---------------- init: v = 1, sv = 1024 --------------------------------------------
__global__ __launch_bounds__(256) void init_v_k(float* __restrict__ vv,
                                                float* __restrict__ svbuf) {
  int id = blockIdx.x * 256 + threadIdx.x;
  if (id < 48 * 1024) vv[id] = 1.0f;
  if (id < 48) svbuf[id] = 1024.0f;
}

// ------ fused Sinkhorn half-sweep: u_i = MU/(sv - D_i·v); colacc += u_i*D_i ---------
// grid (32 stripes, 48 bh); block 256 = 4 waves; wave handles 8 rows.
// lane owns cols [8L..8L+8) (e=0..7) and [512+8L..512+8L+8) (e=8..15).
__global__ __launch_bounds__(256) void sink_k(
    const ushort* __restrict__ SK, const float* __restrict__ vv,
    const float* __restrict__ svbuf, float* __restrict__ u,
    float* __restrict__ colpart, float* __restrict__ supart) {
  const int stripe = blockIdx.x, bh = blockIdx.y;
  const int tid = threadIdx.x, lane = tid & 63, w = tid >> 6;
  const int rstart = stripe * 32 + w * 8;
  const ushort* base = SK + ((size_t)bh << 20);
  const float* vb = vv + (bh << 10);
  const float sv = svbuf[bh];
  float vr[16];
  *(float4*)(vr)      = *(const float4*)(vb + 8 * lane);
  *(float4*)(vr + 4)  = *(const float4*)(vb + 8 * lane + 4);
  *(float4*)(vr + 8)  = *(const float4*)(vb + 512 + 8 * lane);
  *(float4*)(vr + 12) = *(const float4*)(vb + 512 + 8 * lane + 4);
  float ca[16];
#pragma unroll
  for (int e = 0; e < 16; ++e) ca[e] = 0.f;
  float usum = 0.f;
  uint4 z4 = make_uint4(0, 0, 0, 0);
  for (int r = 0; r < 8; ++r) {
    const int i = rstart + r;
    const ushort* row = base + ((size_t)i << 10);
    const int nc8 = i >> 3;
    uint4 da = (lane <= nc8)      ? *(const uint4*)(row + 8 * lane)       : z4;
    uint4 db = (lane + 64 <= nc8) ? *(const uint4*)(row + 512 + 8 * lane) : z4;
    float d[16];
    up8(da, d); up8(db, d + 8);
    float a = 0.f;
#pragma unroll
    for (int e = 0; e < 16; ++e) a += d[e] * vr[e];
#pragma unroll
    for (int o = 1; o < 64; o <<= 1) a += __shfl_xor(a, o);
    const float ui = MU / (sv - a);
    if (lane == 0) u[(bh << 10) + i] = ui;
    usum += ui;
#pragma unroll
    for (int e = 0; e < 16; ++e) ca[e] += ui * d[e];
  }
  __shared__ float cred[4][1024];
  __shared__ float sred[4];
#pragma unroll
  for (int e = 0; e < 16; ++e) cred[w][e * 64 + lane] = ca[e];
  if (lane == 0) sred[w] = usum;
  __syncthreads();
  float* cp = colpart + (((size_t)stripe * 48 + bh) << 10);
#pragma unroll
  for (int pp = 0; pp < 4; ++pp) {
    int p = tid + pp * 256;
    cp[p] = cred[0][p] + cred[1][p] + cred[2][p] + cred[3][p];
  }
  if (tid == 0) supart[stripe * 48 + bh] = sred[0] + sred[1] + sred[2] + sred[3];
}

// ------ finish v-update: v_j = MU/(su - colsum_j); also sv = sum v ------------------
__global__ __launch_bounds__(256) void vfin_k(
    const float* __restrict__ colpart, const float* __restrict__ supart,
    float* __restrict__ vv, float* __restrict__ svbuf) {
  const int bh = blockIdx.x;
  const int tid = threadIdx.x;
  float su = (tid < 32) ? supart[tid * 48 + bh] : 0.f;
#pragma unroll
  for (int o = 1; o < 64; o <<= 1) su += __shfl_xor(su, o);
  __shared__ float s_su;
  __shared__ float red[4];
  if (tid == 0) s_su = su;
  __syncthreads();
  su = s_su;
  float svsum = 0.f;
#pragma unroll
  for (int pp = 0; pp < 4; ++pp) {
    int p = tid + pp * 256;
    float s = 0.f;
    for (int st = 0; st < 32; ++st)
      s += colpart[(((size_t)st * 48 + bh) << 10) + p];
    int e = p >> 6, l = p & 63;
    int c = (e < 8) ? (8 * l + e) : (512 + 8 * l + (e - 8));
    float vn = MU / (su - s);
    vv[(bh << 10) + c] = vn;
    svsum += vn;
  }
  for (int o = 32; o; o >>= 1) svsum += __shfl_down(svsum, o);
  if ((tid & 63) == 0) red[tid >> 6] = svsum;
  __syncthreads();
  if (tid == 0) svbuf[bh] = red[0] + red[1] + red[2] + red[3];
}

// ---------------- V' = v ⊙ V (bf16, d-major) + Wd[bh][d] = sum_t V'[t][d] -----------
__global__ __launch_bounds__(256) void vprep_k(const float* __restrict__ Vt,
                                               const float* __restrict__ vv,
                                               ushort* __restrict__ Vpt,
                                               float* __restrict__ Wd) {
  const int bd = blockIdx.x;            // bh*64 + d
  const int bh = bd >> 6;
  const int tid = threadIdx.x;
  const float* src = Vt + ((size_t)bd << 10);
  const float* vb = vv + (bh << 10);
  ushort* dst = Vpt + ((size_t)bd << 10);
  float s = 0.f;
  for (int t = tid; t < 1024; t += 256) {
    float p = src[t] * vb[t];
    s += p;
    dst[t] = f2bf(p);
  }
  for (int o = 32; o; o >>= 1) s += __shfl_down(s, o);
  __shared__ float red[4];
  if ((tid & 63) == 0) red[tid >> 6] = s;
  __syncthreads();
  if (tid == 0) Wd[bd] = red[0] + red[1] + red[2] + red[3];
}

// ------- y = 1024*u ⊙ (Wd - D @ V'), write [B][T][H*64+d] bf16 (triangular K) -------
__global__ __launch_bounds__(256) void gemm_pv_k(
    const ushort* __restrict__ SK, const ushort* __restrict__ Vpt,
    const float* __restrict__ u, const float* __restrict__ Wd,
    ushort* __restrict__ yb) {
  const int qt = blockIdx.y, bh = blockIdx.z;
  const int arow0 = qt * 64;
  const int brow0 = 0;
  const int kdim = (qt + 1) << 6;
  const ushort* A = SK + ((size_t)bh << 20);
  const ushort* B = Vpt + ((size_t)bh << 16);
  GEMM_PROLOG();
  GEMM_LOOP(A, B, 1024, 1024, kdim);
  const int bb = bh / 12, h = bh - bb * 12;
  GEMM_EPILOG({
    float yv = (Wd[(bh << 6) + gc] - val) * u[(bh << 10) + gr] * 1024.0f;
    yb[((size_t)((bb << 10) + gr)) * 768 + (h << 6) + gc] = f2bf(yv);
  });
}

// ---------------- out = y @ Wp + b_proj (fp32 out) ----------------------------------
__global__ __launch_bounds__(256) void gemm_proj_k(
    const ushort* __restrict__ yb, const ushort* __restrict__ WpT,
    const float* __restrict__ b_proj, float* __restrict__ out) {
  const int arow0 = blockIdx.y * 64;
  const int brow0 = blockIdx.x * 64;
  GEMM_PROLOG();
  GEMM_LOOP(yb, WpT, 768, 768, 768);
  GEMM_EPILOG({ out[(size_t)gr * 768 + gc] = val + b_proj[gc]; });
}

// ------------------------------------------------------------------------------------
extern "C" void kernel_launch(void* const* d_in, const int* in_sizes, int n_in,
                              void* d_out, int out_size, void* d_ws, size_t ws_size,
                              hipStream_t stream) {
  const float* x      = (const float*)d_in[0];
  const float* ln_w   = (const float*)d_in[1];
  const float* ln_b   = (const float*)d_in[2];
  const float* W_attn = (const float*)d_in[3];
  const float* b_attn = (const float*)d_in[4];
  const float* W_proj = (const float*)d_in[5];
  const float* b_proj = (const float*)d_in[6];
  float* out = (float*)d_out;
  char* ws = (char*)d_ws;

  // ws layout (bytes); total ~150.3 MB
  ushort* xnb = (ushort*)(ws + 0);            // 4096*800 bf16
  ushort* WaT = (ushort*)(ws + 6553600);      // 2304*800 bf16
  ushort* WpT = (ushort*)(ws + 10240000);     // 768*768 bf16
  ushort* qb  = (ushort*)(ws + 11419648);     // 48*1024*64 bf16 (dead after gemm_s)
  ushort* kb  = (ushort*)(ws + 17711104);     // 48*1024*64 bf16 (dead after gemm_s)
  float*  Vt  = (float*) (ws + 24002560);     // 48*64*1024 f32 (d-major)
  ushort* SK  = (ushort*)(ws + 36585472);     // 48*1024*1024 bf16 (S, then D)
  ushort* Vpt = (ushort*)(ws + 137248768);    // 48*64*1024 bf16
  ushort* yb  = (ushort*)(ws + 143540224);    // 4096*768 bf16
  float*  u   = (float*) (ws + 149831680);    // 48*1024 f32
  float*  vv  = (float*) (ws + 150028288);    // 48*1024 f32
  float*  Wd  = (float*) (ws + 150224896);    // 48*64 f32
  // overlay on dead qb/kb region (after gemm_s):
  float*  colpart = (float*)(ws + 11419648);  // 32*48*1024 f32 = 6.29MB
  float*  supart  = (float*)(ws + 17711104);  // 32*48 f32
  float*  svbuf   = (float*)(ws + 17717248);  // 48 f32

  hipLaunchKernelGGL(ln_k, dim3(4096), dim3(256), 0, stream, x, ln_w, ln_b, xnb);
  hipLaunchKernelGGL(tr_k, dim3(72, 25), dim3(256), 0, stream, W_attn, WaT, 769, 2304, 800);
  hipLaunchKernelGGL(tr_k, dim3(24, 24), dim3(256), 0, stream, W_proj, WpT, 768, 768, 768);
  hipLaunchKernelGGL(gemm_qkv_k, dim3(36, 64), dim3(256), 0, stream,
                     xnb, WaT, b_attn, qb, kb, Vt);
  hipLaunchKernelGGL(gemm_s_k, dim3(16, 16, 48), dim3(256), 0, stream, qb, kb, SK);
  hipLaunchKernelGGL(kmat_k, dim3(12288), dim3(256), 0, stream, SK);
  hipLaunchKernelGGL(init_v_k, dim3(192), dim3(256), 0, stream, vv, svbuf);
  for (int it = 0; it < 6; ++it) {
    hipLaunchKernelGGL(sink_k, dim3(32, 48), dim3(256), 0, stream,
                       SK, vv, svbuf, u, colpart, supart);
    hipLaunchKernelGGL(vfin_k, dim3(48), dim3(256), 0, stream,
                       colpart, supart, vv, svbuf);
  }
  hipLaunchKernelGGL(vprep_k, dim3(3072), dim3(256), 0, stream, Vt, vv, Vpt, Wd);
  hipLaunchKernelGGL(gemm_pv_k, dim3(1, 16, 48), dim3(256), 0, stream, SK, Vpt, u, Wd, yb);
  hipLaunchKernelGGL(gemm_proj_k, dim3(12, 64), dim3(256), 0, stream, yb, WpT, b_proj, out);
}

// Round 5
// 344.727 us; speedup vs baseline: 3.0314x; 1.0019x over previous
//
#include <hip/hip_runtime.h>

typedef float f32x4 __attribute__((ext_vector_type(4)));
typedef __bf16 bf16x8 __attribute__((ext_vector_type(8)));

#define MU (1.0f / 1024.0f)

__device__ __forceinline__ float bf2f(ushort u) {
  union { uint i; float f; } v; v.i = ((uint)u) << 16; return v.f;
}
__device__ __forceinline__ ushort f2bf(float f) {
  union { float f; uint i; } v; v.f = f;
  uint r = v.i + 0x7fffu + ((v.i >> 16) & 1u);  // RNE
  return (ushort)(r >> 16);
}
__device__ __forceinline__ void up8(uint4 v, float* o) {
  o[0] = bf2f((ushort)v.x); o[1] = bf2f((ushort)(v.x >> 16));
  o[2] = bf2f((ushort)v.y); o[3] = bf2f((ushort)(v.y >> 16));
  o[4] = bf2f((ushort)v.z); o[5] = bf2f((ushort)(v.z >> 16));
  o[6] = bf2f((ushort)v.w); o[7] = bf2f((ushort)(v.w >> 16));
}
__device__ __forceinline__ uint4 pk8(const float* f) {
  uint4 r;
  r.x = (uint)f2bf(f[0]) | ((uint)f2bf(f[1]) << 16);
  r.y = (uint)f2bf(f[2]) | ((uint)f2bf(f[3]) << 16);
  r.z = (uint)f2bf(f[4]) | ((uint)f2bf(f[5]) << 16);
  r.w = (uint)f2bf(f[6]) | ((uint)f2bf(f[7]) << 16);
  return r;
}

// async global->LDS, 16B per lane; lds base must be wave-uniform
typedef const __attribute__((address_space(1))) void gvoid;
typedef __attribute__((address_space(3))) void lvoid;
__device__ __forceinline__ void g2l16(const void* g, void* l) {
  __builtin_amdgcn_global_load_lds((gvoid*)g, (lvoid*)l, 16, 0, 0);
}

// ---------------- LayerNorm: x[4096][769] f32 -> xnb[4096][800] bf16 (zero-pad K) ---
__global__ __launch_bounds__(256) void ln_k(const float* __restrict__ x,
                                            const float* __restrict__ w,
                                            const float* __restrict__ b,
                                            ushort* __restrict__ xnb) {
  const int row = blockIdx.x;
  const int tid = threadIdx.x;
  const float* xr = x + (size_t)row * 769;
  float s = 0.f, ss = 0.f;
  for (int c = tid; c < 769; c += 256) { float v = xr[c]; s += v; ss += v * v; }
  for (int o = 32; o; o >>= 1) { s += __shfl_down(s, o); ss += __shfl_down(ss, o); }
  __shared__ float rs[4], rss[4];
  if ((tid & 63) == 0) { rs[tid >> 6] = s; rss[tid >> 6] = ss; }
  __syncthreads();
  s  = rs[0] + rs[1] + rs[2] + rs[3];
  ss = rss[0] + rss[1] + rss[2] + rss[3];
  const float mean = s * (1.0f / 769.0f);
  const float var  = ss * (1.0f / 769.0f) - mean * mean;
  const float rstd = rsqrtf(var + 1e-5f);
  ushort* orow = xnb + (size_t)row * 800;
  for (int c = tid; c < 800; c += 256) {
    float o = 0.f;
    if (c < 769) o = (xr[c] - mean) * rstd * w[c] + b[c];
    orow[c] = f2bf(o);
  }
}

// ---------------- transpose W[K][N] f32 -> Wt[N][Kp] bf16 (zero-pad K..Kp) ----------
__global__ __launch_bounds__(256) void tr_k(const float* __restrict__ W,
                                            ushort* __restrict__ Wt,
                                            int K, int N, int Kp) {
  __shared__ float ls[32][33];
  const int n0 = blockIdx.x * 32, k0 = blockIdx.y * 32;
  const int c = threadIdx.x & 31, r = threadIdx.x >> 5;  // r in 0..7
  for (int rr = 0; rr < 32; rr += 8) {
    int k = k0 + r + rr;
    ls[r + rr][c] = (k < K) ? W[(size_t)k * N + n0 + c] : 0.f;
  }
  __syncthreads();
  for (int rr = 0; rr < 32; rr += 8) {
    int n = n0 + r + rr;
    if (k0 + c < Kp) Wt[(size_t)n * Kp + k0 + c] = f2bf(ls[c][r + rr]);
  }
}

// ---------------- shared 64x64 GEMM core (used by gemm_s / gemm_pv / gemm_proj) -----
#define GEMM_PROLOG() \
  __shared__ __align__(16) ushort lsA[64 * 40]; \
  __shared__ __align__(16) ushort lsB[64 * 40]; \
  const int tid = threadIdx.x; \
  const int lane = tid & 63; \
  const int wid = tid >> 6; \
  const int wr = wid >> 1, wc = wid & 1; \
  const int l15 = lane & 15, l4 = lane >> 4; \
  const int srow = tid >> 2, scol = (tid & 3) << 3; \
  f32x4 acc00 = {0.f, 0.f, 0.f, 0.f}; \
  f32x4 acc01 = acc00, acc10 = acc00, acc11 = acc00;

#define GEMM_LOOP(Aptr, Btptr, lda, ldb, kdim) \
  { const size_t aoff0 = (size_t)(arow0 + srow) * (lda) + scol; \
    const size_t boff0 = (size_t)(brow0 + srow) * (ldb) + scol; \
    for (int k0 = 0; k0 < (kdim); k0 += 32) { \
      uint4 av = *(const uint4*)((Aptr) + aoff0 + k0); \
      uint4 bv = *(const uint4*)((Btptr) + boff0 + k0); \
      __syncthreads(); \
      *(uint4*)(lsA + srow * 40 + scol) = av; \
      *(uint4*)(lsB + srow * 40 + scol) = bv; \
      __syncthreads(); \
      bf16x8 af0 = *(const bf16x8*)(lsA + (wr * 32 + l15) * 40 + l4 * 8); \
      bf16x8 af1 = *(const bf16x8*)(lsA + (wr * 32 + 16 + l15) * 40 + l4 * 8); \
      bf16x8 bq0 = *(const bf16x8*)(lsB + (wc * 32 + l15) * 40 + l4 * 8); \
      bf16x8 bq1 = *(const bf16x8*)(lsB + (wc * 32 + 16 + l15) * 40 + l4 * 8); \
      acc00 = __builtin_amdgcn_mfma_f32_16x16x32_bf16(af0, bq0, acc00, 0, 0, 0); \
      acc01 = __builtin_amdgcn_mfma_f32_16x16x32_bf16(af0, bq1, acc01, 0, 0, 0); \
      acc10 = __builtin_amdgcn_mfma_f32_16x16x32_bf16(af1, bq0, acc10, 0, 0, 0); \
      acc11 = __builtin_amdgcn_mfma_f32_16x16x32_bf16(af1, bq1, acc11, 0, 0, 0); \
    } }

#define EPI_ONE(ACC, FM, FN, ...) \
  { _Pragma("unroll") for (int r = 0; r < 4; ++r) { \
      int gr = arow0 + wr * 32 + (FM) * 16 + l4 * 4 + r; \
      int gc = brow0 + wc * 32 + (FN) * 16 + l15; \
      float val = ACC[r]; \
      __VA_ARGS__; \
  } }
#define GEMM_EPILOG(...) \
  EPI_ONE(acc00, 0, 0, __VA_ARGS__) EPI_ONE(acc01, 0, 1, __VA_ARGS__) \
  EPI_ONE(acc10, 1, 0, __VA_ARGS__) EPI_ONE(acc11, 1, 1, __VA_ARGS__)

// ------- QKV GEMM, 128x128 tile, global_load_lds staging (m97 structure) ------------
// grid (18 N-tiles, 32 M-tiles), 256 threads = 4 waves (2x2 quadrants of 64x64)
__global__ __launch_bounds__(256) void gemm_qkv_k(
    const ushort* __restrict__ xnb, const ushort* __restrict__ WaT,
    const float* __restrict__ b_attn,
    ushort* __restrict__ qb, ushort* __restrict__ kb, float* __restrict__ Vt) {
  __shared__ __align__(16) ushort lsA[128 * 32];
  __shared__ __align__(16) ushort lsB[128 * 32];
  const int tid = threadIdx.x, lane = tid & 63, w = tid >> 6;
  const int wr = w >> 1, wc = w & 1;
  const int l15 = lane & 15, l4 = lane >> 4;
  const int arow0 = blockIdx.y * 128, brow0 = blockIdx.x * 128;
  const int srow = lane >> 2;            // 0..15 within 16-row segment
  const int scol = (lane & 3) * 8;       // ushort col
  f32x4 acc[4][4];
#pragma unroll
  for (int m = 0; m < 4; ++m)
#pragma unroll
    for (int n = 0; n < 4; ++n) acc[m][n] = (f32x4){0.f, 0.f, 0.f, 0.f};

  const ushort* ga0 = xnb + (size_t)(arow0 + w * 32 + srow) * 800 + scol;
  const ushort* ga1 = xnb + (size_t)(arow0 + w * 32 + 16 + srow) * 800 + scol;
  const ushort* gb0 = WaT + (size_t)(brow0 + w * 32 + srow) * 800 + scol;
  const ushort* gb1 = WaT + (size_t)(brow0 + w * 32 + 16 + srow) * 800 + scol;
  ushort* la0 = lsA + (w * 2) * 512;
  ushort* la1 = lsA + (w * 2 + 1) * 512;
  ushort* lb0 = lsB + (w * 2) * 512;
  ushort* lb1 = lsB + (w * 2 + 1) * 512;

  for (int k0 = 0; k0 < 800; k0 += 32) {
    __syncthreads();                     // prev-iter LDS reads done
    g2l16(ga0 + k0, la0);
    g2l16(ga1 + k0, la1);
    g2l16(gb0 + k0, lb0);
    g2l16(gb1 + k0, lb1);
    __syncthreads();                     // drains vmcnt (compiler waitcnt)
    bf16x8 af[4], bf[4];
#pragma unroll
    for (int m = 0; m < 4; ++m)
      af[m] = *(const bf16x8*)(lsA + (wr * 64 + m * 16 + l15) * 32 + l4 * 8);
#pragma unroll
    for (int n = 0; n < 4; ++n)
      bf[n] = *(const bf16x8*)(lsB + (wc * 64 + n * 16 + l15) * 32 + l4 * 8);
#pragma unroll
    for (int m = 0; m < 4; ++m)
#pragma unroll
      for (int n = 0; n < 4; ++n)
        acc[m][n] = __builtin_amdgcn_mfma_f32_16x16x32_bf16(af[m], bf[n], acc[m][n], 0, 0, 0);
  }

#pragma unroll
  for (int m = 0; m < 4; ++m)
#pragma unroll
    for (int n = 0; n < 4; ++n) {
      const int gc = brow0 + wc * 64 + n * 16 + l15;
      const float bias = b_attn[gc];
      const int sect = gc / 768;
      const int e = gc - sect * 768;
      const int h = e >> 6;
      const int d = e & 63;
      const size_t bhh = (size_t)h;      // head within batch; batch from gr
#pragma unroll
      for (int r = 0; r < 4; ++r) {
        const int gr = arow0 + wr * 64 + m * 16 + l4 * 4 + r;
        const int bb = gr >> 10;
        const int t = gr & 1023;
        const size_t bh = (size_t)(bb * 12) + bhh;
        const float val = acc[m][n][r] + bias;
        if (sect == 0)      qb[(bh << 16) + ((size_t)t << 6) + d] = f2bf(val * 0.125f);
        else if (sect == 1) kb[(bh << 16) + ((size_t)t << 6) + d] = f2bf(val);
        else                Vt[(bh << 16) + ((size_t)d << 10) + t] = val;
      }
    }
}

// ---------------- S = q k^T per (b,h): store bf16 logits (lower triangle tiles) -----
__global__ __launch_bounds__(256) void gemm_s_k(
    const ushort* __restrict__ qb, const ushort* __restrict__ kb,
    ushort* __restrict__ SK) {
  const int kt = blockIdx.x, qt = blockIdx.y, bh = blockIdx.z;
  if (kt > qt) return;  // strictly above diagonal: never read
  const int arow0 = qt * 64;
  const int brow0 = kt * 64;
  const ushort* A = qb + ((size_t)bh << 16);
  const ushort* B = kb + ((size_t)bh << 16);
  ushort* S = SK + ((size_t)bh << 20);
  GEMM_PROLOG();
  GEMM_LOOP(A, B, 64, 64, 64);
  GEMM_EPILOG({ S[((size_t)gr << 10) + gc] = f2bf(val); });
}

// ---- row softmax p, then D = 1-exp(-p). Writes only up to 64-col diag band. --------
__global__ __launch_bounds__(256) void kmat_k(ushort* __restrict__ SK) {
  const int tid = threadIdx.x, lane = tid & 63, w = tid >> 6;
  const int rg = blockIdx.x * 4 + w;        // global row index 0..49151
  const int i = rg & 1023;
  ushort* row = SK + ((size_t)rg << 10);
  const int nc8 = i >> 3;                   // last chunk containing valid cols
  const int cA = lane, cB = lane + 64;
  uint4 z4 = make_uint4(0, 0, 0, 0);
  uint4 da = (cA <= nc8) ? *(const uint4*)(row + 8 * cA) : z4;
  uint4 db = (cB <= nc8) ? *(const uint4*)(row + 8 * cB) : z4;
  float xa[8], xb[8];
  up8(da, xa); up8(db, xb);
  float m = -1e30f;
#pragma unroll
  for (int e = 0; e < 8; ++e) {
    if (8 * cA + e <= i) m = fmaxf(m, xa[e]);
    if (8 * cB + e <= i) m = fmaxf(m, xb[e]);
  }
#pragma unroll
  for (int o = 1; o < 64; o <<= 1) m = fmaxf(m, __shfl_xor(m, o));
  float pa[8], pb[8];
  float s = 0.f;
#pragma unroll
  for (int e = 0; e < 8; ++e) {
    pa[e] = (8 * cA + e <= i) ? __expf(xa[e] - m) : 0.f;
    pb[e] = (8 * cB + e <= i) ? __expf(xb[e] - m) : 0.f;
    s += pa[e] + pb[e];
  }
#pragma unroll
  for (int o = 1; o < 64; o <<= 1) s += __shfl_xor(s, o);
  const float inv = 1.0f / s;
  float Da[8], Db[8];
#pragma unroll
  for (int e = 0; e < 8; ++e) {
    Da[e] = (8 * cA + e <= i) ? (1.0f - __expf(-pa[e] * inv)) : 0.f;
    Db[e] = (8 * cB + e <= i) ? (1.0f - __expf(-pb[e] * inv)) : 0.f;
  }
  const int bandc = ((i >> 6) + 1) << 3;    // chunks up to diag-band boundary
  if (cA < bandc) *(uint4*)(row + 8 * cA) = pk8(Da);
  if (cB < bandc) *(uint4*)(row + 8 * cB) = pk8(Db);
}

// ---------------- init: v = 1 -------------------------------------------------------
__global__ __launch_bounds__(256) void init_v_k(float* __restrict__ vv) {
  int id = blockIdx.x * 256 + threadIdx.x;
  if (id < 48 * 1024) vv[id] = 1.0f;
}

// ------ fused Sinkhorn half-sweep: u_i = MU/(sv - D_i·v); colacc += u_i*D_i ---------
// grid (32 stripes reversed, 48 bh); 4 waves; wave handles 8 rows.
__global__ __launch_bounds__(256) void sink_k(
    const ushort* __restrict__ SK, const float* __restrict__ vv,
    float* __restrict__ u, float* __restrict__ colpart) {
  const int stripe = 31 - blockIdx.x;   // heavy (bottom) stripes launch first
  const int bh = blockIdx.y;
  const int tid = threadIdx.x, lane = tid & 63, w = tid >> 6;
  const int rstart = stripe * 32 + w * 8;
  const ushort* base = SK + ((size_t)bh << 20);
  const float* vb = vv + (bh << 10);
  float vr[16];
  *(float4*)(vr)      = *(const float4*)(vb + 8 * lane);
  *(float4*)(vr + 4)  = *(const float4*)(vb + 8 * lane + 4);
  *(float4*)(vr + 8)  = *(const float4*)(vb + 512 + 8 * lane);
  *(float4*)(vr + 12) = *(const float4*)(vb + 512 + 8 * lane + 4);
  float sv = 0.f;
#pragma unroll
  for (int e = 0; e < 16; ++e) sv += vr[e];
#pragma unroll
  for (int o = 1; o < 64; o <<= 1) sv += __shfl_xor(sv, o);
  float ca[16];
#pragma unroll
  for (int e = 0; e < 16; ++e) ca[e] = 0.f;
  uint4 z4 = make_uint4(0, 0, 0, 0);
  for (int r = 0; r < 8; ++r) {
    const int i = rstart + r;
    const ushort* row = base + ((size_t)i << 10);
    const int nc8 = i >> 3;
    uint4 da = (lane <= nc8)      ? *(const uint4*)(row + 8 * lane)       : z4;
    uint4 db = (lane + 64 <= nc8) ? *(const uint4*)(row + 512 + 8 * lane) : z4;
    float d[16];
    up8(da, d); up8(db, d + 8);
    float a = 0.f;
#pragma unroll
    for (int e = 0; e < 16; ++e) a += d[e] * vr[e];
#pragma unroll
    for (int o = 1; o < 64; o <<= 1) a += __shfl_xor(a, o);
    const float ui = MU / (sv - a);
    if (lane == 0) u[(bh << 10) + i] = ui;
#pragma unroll
    for (int e = 0; e < 16; ++e) ca[e] += ui * d[e];
  }
  __shared__ float cred[4][1024];
#pragma unroll
  for (int e = 0; e < 16; ++e) cred[w][e * 64 + lane] = ca[e];
  __syncthreads();
  float* cp = colpart + (((size_t)stripe * 48 + bh) << 10);
#pragma unroll
  for (int pp = 0; pp < 4; ++pp) {
    int p = tid + pp * 256;
    cp[p] = cred[0][p] + cred[1][p] + cred[2][p] + cred[3][p];
  }
}

// ------ finish v-update: v_j = MU/(su - colsum_j). grid (4 col-chunks, 48 bh) -------
__global__ __launch_bounds__(256) void vfin_k(
    const float* __restrict__ colpart, const float* __restrict__ u,
    float* __restrict__ vv) {
  const int cq = blockIdx.x, bh = blockIdx.y;
  const int tid = threadIdx.x;
  float su = 0.f;
  for (int t = tid; t < 1024; t += 256) su += u[(bh << 10) + t];
#pragma unroll
  for (int o = 1; o < 64; o <<= 1) su += __shfl_xor(su, o);
  __shared__ float red[4];
  if ((tid & 63) == 0) red[tid >> 6] = su;
  __syncthreads();
  su = red[0] + red[1] + red[2] + red[3];
  const int c = cq * 256 + tid;
  int p;
  if (c < 512) p = (c & 7) * 64 + (c >> 3);
  else         p = (8 + ((c - 512) & 7)) * 64 + ((c - 512) >> 3);
  float s = 0.f;
  for (int st = 0; st < 32; ++st)
    s += colpart[(((size_t)st * 48 + bh) << 10) + p];
  vv[(bh << 10) + c] = MU / (su - s);
}

// ---------------- V' = v ⊙ V (bf16, d-major) + Wd[bh][d] = sum_t V'[t][d] -----------
__global__ __launch_bounds__(256) void vprep_k(const float* __restrict__ Vt,
                                               const float* __restrict__ vv,
                                               ushort* __restrict__ Vpt,
                                               float* __restrict__ Wd) {
  const int bd = blockIdx.x;            // bh*64 + d
  const int bh = bd >> 6;
  const int tid = threadIdx.x;
  const float* src = Vt + ((size_t)bd << 10);
  const float* vb = vv + (bh << 10);
  ushort* dst = Vpt + ((size_t)bd << 10);
  float s = 0.f;
  for (int t = tid; t < 1024; t += 256) {
    float p = src[t] * vb[t];
    s += p;
    dst[t] = f2bf(p);
  }
  for (int o = 32; o; o >>= 1) s += __shfl_down(s, o);
  __shared__ float red[4];
  if ((tid & 63) == 0) red[tid >> 6] = s;
  __syncthreads();
  if (tid == 0) Wd[bd] = red[0] + red[1] + red[2] + red[3];
}

// ------- y = 1024*u ⊙ (Wd - D @ V'), write [B][T][H*64+d] bf16 (triangular K) -------
__global__ __launch_bounds__(256) void gemm_pv_k(
    const ushort* __restrict__ SK, const ushort* __restrict__ Vpt,
    const float* __restrict__ u, const float* __restrict__ Wd,
    ushort* __restrict__ yb) {
  const int qt = blockIdx.y, bh = blockIdx.z;
  const int arow0 = qt * 64;
  const int brow0 = 0;
  const int kdim = (qt + 1) << 6;
  const ushort* A = SK + ((size_t)bh << 20);
  const ushort* B = Vpt + ((size_t)bh << 16);
  GEMM_PROLOG();
  GEMM_LOOP(A, B, 1024, 1024, kdim);
  const int bb = bh / 12, h = bh - bb * 12;
  GEMM_EPILOG({
    float yv = (Wd[(bh << 6) + gc] - val) * u[(bh << 10) + gr] * 1024.0f;
    yb[((size_t)((bb << 10) + gr)) * 768 + (h << 6) + gc] = f2bf(yv);
  });
}

// ---------------- out = y @ Wp + b_proj (fp32 out) ----------------------------------
__global__ __launch_bounds__(256) void gemm_proj_k(
    const ushort* __restrict__ yb, const ushort* __restrict__ WpT,
    const float* __restrict__ b_proj, float* __restrict__ out) {
  const int arow0 = blockIdx.y * 64;
  const int brow0 = blockIdx.x * 64;
  GEMM_PROLOG();
  GEMM_LOOP(yb, WpT, 768, 768, 768);
  GEMM_EPILOG({ out[(size_t)gr * 768 + gc] = val + b_proj[gc]; });
}

// ------------------------------------------------------------------------------------
extern "C" void kernel_launch(void* const* d_in, const int* in_sizes, int n_in,
                              void* d_out, int out_size, void* d_ws, size_t ws_size,
                              hipStream_t stream) {
  const float* x      = (const float*)d_in[0];
  const float* ln_w   = (const float*)d_in[1];
  const float* ln_b   = (const float*)d_in[2];
  const float* W_attn = (const float*)d_in[3];
  const float* b_attn = (const float*)d_in[4];
  const float* W_proj = (const float*)d_in[5];
  const float* b_proj = (const float*)d_in[6];
  float* out = (float*)d_out;
  char* ws = (char*)d_ws;

  // ws layout (bytes); total ~150.3 MB
  ushort* xnb = (ushort*)(ws + 0);            // 4096*800 bf16
  ushort* WaT = (ushort*)(ws + 6553600);      // 2304*800 bf16
  ushort* WpT = (ushort*)(ws + 10240000);     // 768*768 bf16
  ushort* qb  = (ushort*)(ws + 11419648);     // 48*1024*64 bf16 (dead after gemm_s)
  ushort* kb  = (ushort*)(ws + 17711104);     // 48*1024*64 bf16 (dead after gemm_s)
  float*  Vt  = (float*) (ws + 24002560);     // 48*64*1024 f32 (d-major)
  ushort* SK  = (ushort*)(ws + 36585472);     // 48*1024*1024 bf16 (S, then D)
  ushort* Vpt = (ushort*)(ws + 137248768);    // 48*64*1024 bf16
  ushort* yb  = (ushort*)(ws + 143540224);    // 4096*768 bf16
  float*  u   = (float*) (ws + 149831680);    // 48*1024 f32
  float*  vv  = (float*) (ws + 150028288);    // 48*1024 f32
  float*  Wd  = (float*) (ws + 150224896);    // 48*64 f32
  // overlay on dead qb/kb region (after gemm_s):
  float*  colpart = (float*)(ws + 11419648);  // 32*48*1024 f32 = 6.29MB

  hipLaunchKernelGGL(ln_k, dim3(4096), dim3(256), 0, stream, x, ln_w, ln_b, xnb);
  hipLaunchKernelGGL(tr_k, dim3(72, 25), dim3(256), 0, stream, W_attn, WaT, 769, 2304, 800);
  hipLaunchKernelGGL(tr_k, dim3(24, 24), dim3(256), 0, stream, W_proj, WpT, 768, 768, 768);
  hipLaunchKernelGGL(gemm_qkv_k, dim3(18, 32), dim3(256), 0, stream,
                     xnb, WaT, b_attn, qb, kb, Vt);
  hipLaunchKernelGGL(gemm_s_k, dim3(16, 16, 48), dim3(256), 0, stream, qb, kb, SK);
  hipLaunchKernelGGL(kmat_k, dim3(12288), dim3(256), 0, stream, SK);
  hipLaunchKernelGGL(init_v_k, dim3(192), dim3(256), 0, stream, vv);
  for (int it = 0; it < 6; ++it) {
    hipLaunchKernelGGL(sink_k, dim3(32, 48), dim3(256), 0, stream, SK, vv, u, colpart);
    hipLaunchKernelGGL(vfin_k, dim3(4, 48), dim3(256), 0, stream, colpart, u, vv);
  }
  hipLaunchKernelGGL(vprep_k, dim3(3072), dim3(256), 0, stream, Vt, vv, Vpt, Wd);
  hipLaunchKernelGGL(gemm_pv_k, dim3(1, 16, 48), dim3(256), 0, stream, SK, Vpt, u, Wd, yb);
  hipLaunchKernelGGL(gemm_proj_k, dim3(12, 64), dim3(256), 0, stream, yb, WpT, b_proj, out);
}

// Round 6
// 319.781 us; speedup vs baseline: 3.2678x; 1.0780x over previous
//
#include <hip/hip_runtime.h>

typedef float f32x4 __attribute__((ext_vector_type(4)));
typedef __bf16 bf16x8 __attribute__((ext_vector_type(8)));

#define MU (1.0f / 1024.0f)

__device__ __forceinline__ float bf2f(ushort u) {
  union { uint i; float f; } v; v.i = ((uint)u) << 16; return v.f;
}
__device__ __forceinline__ ushort f2bf(float f) {
  union { float f; uint i; } v; v.f = f;
  uint r = v.i + 0x7fffu + ((v.i >> 16) & 1u);  // RNE
  return (ushort)(r >> 16);
}
__device__ __forceinline__ void up8(uint4 v, float* o) {
  o[0] = bf2f((ushort)v.x); o[1] = bf2f((ushort)(v.x >> 16));
  o[2] = bf2f((ushort)v.y); o[3] = bf2f((ushort)(v.y >> 16));
  o[4] = bf2f((ushort)v.z); o[5] = bf2f((ushort)(v.z >> 16));
  o[6] = bf2f((ushort)v.w); o[7] = bf2f((ushort)(v.w >> 16));
}
__device__ __forceinline__ uint4 pk8(const float* f) {
  uint4 r;
  r.x = (uint)f2bf(f[0]) | ((uint)f2bf(f[1]) << 16);
  r.y = (uint)f2bf(f[2]) | ((uint)f2bf(f[3]) << 16);
  r.z = (uint)f2bf(f[4]) | ((uint)f2bf(f[5]) << 16);
  r.w = (uint)f2bf(f[6]) | ((uint)f2bf(f[7]) << 16);
  return r;
}

// async global->LDS, 16B per lane; lds base must be wave-uniform
typedef const __attribute__((address_space(1))) void gvoid;
typedef __attribute__((address_space(3))) void lvoid;
__device__ __forceinline__ void g2l16(const void* g, void* l) {
  __builtin_amdgcn_global_load_lds((gvoid*)g, (lvoid*)l, 16, 0, 0);
}

// ---------------- LayerNorm: x[4096][769] f32 -> xnb[4096][800] bf16 (zero-pad K) ---
__global__ __launch_bounds__(256) void ln_k(const float* __restrict__ x,
                                            const float* __restrict__ w,
                                            const float* __restrict__ b,
                                            ushort* __restrict__ xnb) {
  const int row = blockIdx.x;
  const int tid = threadIdx.x;
  const float* xr = x + (size_t)row * 769;
  float s = 0.f, ss = 0.f;
  for (int c = tid; c < 769; c += 256) { float v = xr[c]; s += v; ss += v * v; }
  for (int o = 32; o; o >>= 1) { s += __shfl_down(s, o); ss += __shfl_down(ss, o); }
  __shared__ float rs[4], rss[4];
  if ((tid & 63) == 0) { rs[tid >> 6] = s; rss[tid >> 6] = ss; }
  __syncthreads();
  s  = rs[0] + rs[1] + rs[2] + rs[3];
  ss = rss[0] + rss[1] + rss[2] + rss[3];
  const float mean = s * (1.0f / 769.0f);
  const float var  = ss * (1.0f / 769.0f) - mean * mean;
  const float rstd = rsqrtf(var + 1e-5f);
  ushort* orow = xnb + (size_t)row * 800;
  for (int c = tid; c < 800; c += 256) {
    float o = 0.f;
    if (c < 769) o = (xr[c] - mean) * rstd * w[c] + b[c];
    orow[c] = f2bf(o);
  }
}

// ---------------- transpose W[K][N] f32 -> Wt[N][Kp] bf16 (zero-pad K..Kp) ----------
__global__ __launch_bounds__(256) void tr_k(const float* __restrict__ W,
                                            ushort* __restrict__ Wt,
                                            int K, int N, int Kp) {
  __shared__ float ls[32][33];
  const int n0 = blockIdx.x * 32, k0 = blockIdx.y * 32;
  const int c = threadIdx.x & 31, r = threadIdx.x >> 5;  // r in 0..7
  for (int rr = 0; rr < 32; rr += 8) {
    int k = k0 + r + rr;
    ls[r + rr][c] = (k < K) ? W[(size_t)k * N + n0 + c] : 0.f;
  }
  __syncthreads();
  for (int rr = 0; rr < 32; rr += 8) {
    int n = n0 + r + rr;
    if (k0 + c < Kp) Wt[(size_t)n * Kp + k0 + c] = f2bf(ls[c][r + rr]);
  }
}

// ---------------- shared 64x64 GEMM core (used by gemm_s / gemm_pv) -----------------
#define GEMM_PROLOG() \
  __shared__ __align__(16) ushort lsA[64 * 40]; \
  __shared__ __align__(16) ushort lsB[64 * 40]; \
  const int tid = threadIdx.x; \
  const int lane = tid & 63; \
  const int wid = tid >> 6; \
  const int wr = wid >> 1, wc = wid & 1; \
  const int l15 = lane & 15, l4 = lane >> 4; \
  const int srow = tid >> 2, scol = (tid & 3) << 3; \
  f32x4 acc00 = {0.f, 0.f, 0.f, 0.f}; \
  f32x4 acc01 = acc00, acc10 = acc00, acc11 = acc00;

#define GEMM_LOOP(Aptr, Btptr, lda, ldb, kdim) \
  { const size_t aoff0 = (size_t)(arow0 + srow) * (lda) + scol; \
    const size_t boff0 = (size_t)(brow0 + srow) * (ldb) + scol; \
    for (int k0 = 0; k0 < (kdim); k0 += 32) { \
      uint4 av = *(const uint4*)((Aptr) + aoff0 + k0); \
      uint4 bv = *(const uint4*)((Btptr) + boff0 + k0); \
      __syncthreads(); \
      *(uint4*)(lsA + srow * 40 + scol) = av; \
      *(uint4*)(lsB + srow * 40 + scol) = bv; \
      __syncthreads(); \
      bf16x8 af0 = *(const bf16x8*)(lsA + (wr * 32 + l15) * 40 + l4 * 8); \
      bf16x8 af1 = *(const bf16x8*)(lsA + (wr * 32 + 16 + l15) * 40 + l4 * 8); \
      bf16x8 bq0 = *(const bf16x8*)(lsB + (wc * 32 + l15) * 40 + l4 * 8); \
      bf16x8 bq1 = *(const bf16x8*)(lsB + (wc * 32 + 16 + l15) * 40 + l4 * 8); \
      acc00 = __builtin_amdgcn_mfma_f32_16x16x32_bf16(af0, bq0, acc00, 0, 0, 0); \
      acc01 = __builtin_amdgcn_mfma_f32_16x16x32_bf16(af0, bq1, acc01, 0, 0, 0); \
      acc10 = __builtin_amdgcn_mfma_f32_16x16x32_bf16(af1, bq0, acc10, 0, 0, 0); \
      acc11 = __builtin_amdgcn_mfma_f32_16x16x32_bf16(af1, bq1, acc11, 0, 0, 0); \
    } }

#define EPI_ONE(ACC, FM, FN, ...) \
  { _Pragma("unroll") for (int r = 0; r < 4; ++r) { \
      int gr = arow0 + wr * 32 + (FM) * 16 + l4 * 4 + r; \
      int gc = brow0 + wc * 32 + (FN) * 16 + l15; \
      float val = ACC[r]; \
      __VA_ARGS__; \
  } }
#define GEMM_EPILOG(...) \
  EPI_ONE(acc00, 0, 0, __VA_ARGS__) EPI_ONE(acc01, 0, 1, __VA_ARGS__) \
  EPI_ONE(acc10, 1, 0, __VA_ARGS__) EPI_ONE(acc11, 1, 1, __VA_ARGS__)

// -------- 128x128 tile, 2-phase double-buffered (T3-minimum), BK=32 -----------------
#define TILE128_PROLOG() \
  __shared__ __align__(16) ushort lsA[2][128 * 32]; \
  __shared__ __align__(16) ushort lsB[2][128 * 32]; \
  const int tid = threadIdx.x, lane = tid & 63, w = tid >> 6; \
  const int wr = w >> 1, wc = w & 1; \
  const int l15 = lane & 15, l4 = lane >> 4; \
  const int scol = (lane & 3) * 8; \
  const int srow = lane >> 2; \
  f32x4 acc[4][4]; \
  _Pragma("unroll") for (int m = 0; m < 4; ++m) \
    _Pragma("unroll") for (int n = 0; n < 4; ++n) acc[m][n] = (f32x4){0.f, 0.f, 0.f, 0.f};

#define TILE128_LOOP(Aptr, Btptr, lda, ldb, kdim) { \
  const ushort* ga0 = (Aptr) + (size_t)(arow0 + w * 32 + srow) * (lda) + scol; \
  const ushort* ga1 = ga0 + 16 * (lda); \
  const ushort* gb0 = (Btptr) + (size_t)(brow0 + w * 32 + srow) * (ldb) + scol; \
  const ushort* gb1 = gb0 + 16 * (ldb); \
  g2l16(ga0, &lsA[0][(w * 2) * 512]); \
  g2l16(ga1, &lsA[0][(w * 2 + 1) * 512]); \
  g2l16(gb0, &lsB[0][(w * 2) * 512]); \
  g2l16(gb1, &lsB[0][(w * 2 + 1) * 512]); \
  __syncthreads(); \
  int cur = 0; \
  for (int k0 = 0; k0 < (kdim); k0 += 32) { \
    if (k0 + 32 < (kdim)) { \
      g2l16(ga0 + k0 + 32, &lsA[cur ^ 1][(w * 2) * 512]); \
      g2l16(ga1 + k0 + 32, &lsA[cur ^ 1][(w * 2 + 1) * 512]); \
      g2l16(gb0 + k0 + 32, &lsB[cur ^ 1][(w * 2) * 512]); \
      g2l16(gb1 + k0 + 32, &lsB[cur ^ 1][(w * 2 + 1) * 512]); \
    } \
    bf16x8 af[4], bq[4]; \
    _Pragma("unroll") for (int m = 0; m < 4; ++m) \
      af[m] = *(const bf16x8*)(&lsA[cur][(wr * 64 + m * 16 + l15) * 32 + l4 * 8]); \
    _Pragma("unroll") for (int n = 0; n < 4; ++n) \
      bq[n] = *(const bf16x8*)(&lsB[cur][(wc * 64 + n * 16 + l15) * 32 + l4 * 8]); \
    _Pragma("unroll") for (int m = 0; m < 4; ++m) \
      _Pragma("unroll") for (int n = 0; n < 4; ++n) \
        acc[m][n] = __builtin_amdgcn_mfma_f32_16x16x32_bf16(af[m], bq[n], acc[m][n], 0, 0, 0); \
    __syncthreads(); \
    cur ^= 1; \
  } }

// ------- QKV GEMM, 128x128 tile 2-phase; grid (18, 32) ------------------------------
__global__ __launch_bounds__(256) void gemm_qkv_k(
    const ushort* __restrict__ xnb, const ushort* __restrict__ WaT,
    const float* __restrict__ b_attn,
    ushort* __restrict__ qb, ushort* __restrict__ kb, float* __restrict__ Vt) {
  const int arow0 = blockIdx.y * 128, brow0 = blockIdx.x * 128;
  TILE128_PROLOG();
  TILE128_LOOP(xnb, WaT, 800, 800, 800);
#pragma unroll
  for (int m = 0; m < 4; ++m)
#pragma unroll
    for (int n = 0; n < 4; ++n) {
      const int gc = brow0 + wc * 64 + n * 16 + l15;
      const float bias = b_attn[gc];
      const int sect = gc / 768;
      const int e = gc - sect * 768;
      const int h = e >> 6;
      const int d = e & 63;
#pragma unroll
      for (int r = 0; r < 4; ++r) {
        const int gr = arow0 + wr * 64 + m * 16 + l4 * 4 + r;
        const int bb = gr >> 10;
        const int t = gr & 1023;
        const size_t bh = (size_t)(bb * 12 + h);
        const float val = acc[m][n][r] + bias;
        if (sect == 0)      qb[(bh << 16) + ((size_t)t << 6) + d] = f2bf(val * 0.125f);
        else if (sect == 1) kb[(bh << 16) + ((size_t)t << 6) + d] = f2bf(val);
        else                Vt[(bh << 16) + ((size_t)d << 10) + t] = val;
      }
    }
}

// ------- proj GEMM: out = yb[4096][768] @ WpT[768][768]^T + b, 128x128 2-phase ------
__global__ __launch_bounds__(256) void gemm_proj_k(
    const ushort* __restrict__ yb, const ushort* __restrict__ WpT,
    const float* __restrict__ b_proj, float* __restrict__ out) {
  const int arow0 = blockIdx.y * 128, brow0 = blockIdx.x * 128;
  TILE128_PROLOG();
  TILE128_LOOP(yb, WpT, 768, 768, 768);
#pragma unroll
  for (int m = 0; m < 4; ++m)
#pragma unroll
    for (int n = 0; n < 4; ++n) {
      const int gc = brow0 + wc * 64 + n * 16 + l15;
      const float bias = b_proj[gc];
#pragma unroll
      for (int r = 0; r < 4; ++r) {
        const int gr = arow0 + wr * 64 + m * 16 + l4 * 4 + r;
        out[(size_t)gr * 768 + gc] = acc[m][n][r] + bias;
      }
    }
}

// ---------------- S = q k^T per (b,h): store bf16 logits (lower triangle tiles) -----
__global__ __launch_bounds__(256) void gemm_s_k(
    const ushort* __restrict__ qb, const ushort* __restrict__ kb,
    ushort* __restrict__ SK) {
  const int kt = blockIdx.x, qt = blockIdx.y, bh = blockIdx.z;
  if (kt > qt) return;  // strictly above diagonal: never read
  const int arow0 = qt * 64;
  const int brow0 = kt * 64;
  const ushort* A = qb + ((size_t)bh << 16);
  const ushort* B = kb + ((size_t)bh << 16);
  ushort* S = SK + ((size_t)bh << 20);
  GEMM_PROLOG();
  GEMM_LOOP(A, B, 64, 64, 64);
  GEMM_EPILOG({ S[((size_t)gr << 10) + gc] = f2bf(val); });
}

// ---- row softmax p, then D = 1-exp(-p). Writes only up to 64-col diag band. --------
__global__ __launch_bounds__(256) void kmat_k(ushort* __restrict__ SK) {
  const int tid = threadIdx.x, lane = tid & 63, w = tid >> 6;
  const int rg = blockIdx.x * 4 + w;        // global row index 0..49151
  const int i = rg & 1023;
  ushort* row = SK + ((size_t)rg << 10);
  const int nc8 = i >> 3;                   // last chunk containing valid cols
  const int cA = lane, cB = lane + 64;
  uint4 z4 = make_uint4(0, 0, 0, 0);
  uint4 da = (cA <= nc8) ? *(const uint4*)(row + 8 * cA) : z4;
  uint4 db = (cB <= nc8) ? *(const uint4*)(row + 8 * cB) : z4;
  float xa[8], xb[8];
  up8(da, xa); up8(db, xb);
  float m = -1e30f;
#pragma unroll
  for (int e = 0; e < 8; ++e) {
    if (8 * cA + e <= i) m = fmaxf(m, xa[e]);
    if (8 * cB + e <= i) m = fmaxf(m, xb[e]);
  }
#pragma unroll
  for (int o = 1; o < 64; o <<= 1) m = fmaxf(m, __shfl_xor(m, o));
  float pa[8], pb[8];
  float s = 0.f;
#pragma unroll
  for (int e = 0; e < 8; ++e) {
    pa[e] = (8 * cA + e <= i) ? __expf(xa[e] - m) : 0.f;
    pb[e] = (8 * cB + e <= i) ? __expf(xb[e] - m) : 0.f;
    s += pa[e] + pb[e];
  }
#pragma unroll
  for (int o = 1; o < 64; o <<= 1) s += __shfl_xor(s, o);
  const float inv = 1.0f / s;
  float Da[8], Db[8];
#pragma unroll
  for (int e = 0; e < 8; ++e) {
    Da[e] = (8 * cA + e <= i) ? (1.0f - __expf(-pa[e] * inv)) : 0.f;
    Db[e] = (8 * cB + e <= i) ? (1.0f - __expf(-pb[e] * inv)) : 0.f;
  }
  const int bandc = ((i >> 6) + 1) << 3;    // chunks up to diag-band boundary
  if (cA < bandc) *(uint4*)(row + 8 * cA) = pk8(Da);
  if (cB < bandc) *(uint4*)(row + 8 * cB) = pk8(Db);
}

// ---------------- init: v = 1 -------------------------------------------------------
__global__ __launch_bounds__(256) void init_v_k(float* __restrict__ vv) {
  int id = blockIdx.x * 256 + threadIdx.x;
  if (id < 48 * 1024) vv[id] = 1.0f;
}

// ------ fused Sinkhorn half-sweep: u_i = MU/(sv - D_i·v); colacc += u_i*D_i ---------
// grid (16 stripe-pairs, 48 bh); block = 4 waves; each block does stripes 31-p and p
// (heavy + light = uniform work). Wave handles 8 rows per stripe.
__global__ __launch_bounds__(256) void sink_k(
    const ushort* __restrict__ SK, const float* __restrict__ vv,
    float* __restrict__ u, float* __restrict__ colpart) {
  const int pair = blockIdx.x, bh = blockIdx.y;
  const int tid = threadIdx.x, lane = tid & 63, w = tid >> 6;
  const ushort* base = SK + ((size_t)bh << 20);
  const float* vb = vv + (bh << 10);
  float vr[16];
  *(float4*)(vr)      = *(const float4*)(vb + 8 * lane);
  *(float4*)(vr + 4)  = *(const float4*)(vb + 8 * lane + 4);
  *(float4*)(vr + 8)  = *(const float4*)(vb + 512 + 8 * lane);
  *(float4*)(vr + 12) = *(const float4*)(vb + 512 + 8 * lane + 4);
  float sv = 0.f;
#pragma unroll
  for (int e = 0; e < 16; ++e) sv += vr[e];
#pragma unroll
  for (int o = 1; o < 64; o <<= 1) sv += __shfl_xor(sv, o);
  __shared__ float cred[4][1024];
  uint4 z4 = make_uint4(0, 0, 0, 0);
  for (int half = 0; half < 2; ++half) {
    const int stripe = half ? pair : (31 - pair);
    const int rstart = stripe * 32 + w * 8;
    float ca[16];
#pragma unroll
    for (int e = 0; e < 16; ++e) ca[e] = 0.f;
    for (int r = 0; r < 8; ++r) {
      const int i = rstart + r;
      const ushort* row = base + ((size_t)i << 10);
      const int nc8 = i >> 3;
      uint4 da = (lane <= nc8)      ? *(const uint4*)(row + 8 * lane)       : z4;
      uint4 db = (lane + 64 <= nc8) ? *(const uint4*)(row + 512 + 8 * lane) : z4;
      float d[16];
      up8(da, d); up8(db, d + 8);
      float a = 0.f;
#pragma unroll
      for (int e = 0; e < 16; ++e) a += d[e] * vr[e];
#pragma unroll
      for (int o = 1; o < 64; o <<= 1) a += __shfl_xor(a, o);
      const float ui = MU / (sv - a);
      if (lane == 0) u[(bh << 10) + i] = ui;
#pragma unroll
      for (int e = 0; e < 16; ++e) ca[e] += ui * d[e];
    }
    if (half) __syncthreads();   // protect cred reuse across halves
#pragma unroll
    for (int e = 0; e < 16; ++e) cred[w][e * 64 + lane] = ca[e];
    __syncthreads();
    float* cp = colpart + (((size_t)stripe * 48 + bh) << 10);
#pragma unroll
    for (int pp = 0; pp < 4; ++pp) {
      int p = tid + pp * 256;
      cp[p] = cred[0][p] + cred[1][p] + cred[2][p] + cred[3][p];
    }
  }
}

// ------ finish v-update: v_j = MU/(su - colsum_j). grid (4 col-chunks, 48 bh) -------
__global__ __launch_bounds__(256) void vfin_k(
    const float* __restrict__ colpart, const float* __restrict__ u,
    float* __restrict__ vv) {
  const int cq = blockIdx.x, bh = blockIdx.y;
  const int tid = threadIdx.x;
  float su = 0.f;
  for (int t = tid; t < 1024; t += 256) su += u[(bh << 10) + t];
#pragma unroll
  for (int o = 1; o < 64; o <<= 1) su += __shfl_xor(su, o);
  __shared__ float red[4];
  if ((tid & 63) == 0) red[tid >> 6] = su;
  __syncthreads();
  su = red[0] + red[1] + red[2] + red[3];
  const int c = cq * 256 + tid;
  int p;
  if (c < 512) p = (c & 7) * 64 + (c >> 3);
  else         p = (8 + ((c - 512) & 7)) * 64 + ((c - 512) >> 3);
  float s = 0.f;
  for (int st = 0; st < 32; ++st)
    s += colpart[(((size_t)st * 48 + bh) << 10) + p];
  vv[(bh << 10) + c] = MU / (su - s);
}

// ---------------- V' = v ⊙ V (bf16, d-major) + Wd[bh][d] = sum_t V'[t][d] -----------
__global__ __launch_bounds__(256) void vprep_k(const float* __restrict__ Vt,
                                               const float* __restrict__ vv,
                                               ushort* __restrict__ Vpt,
                                               float* __restrict__ Wd) {
  const int bd = blockIdx.x;            // bh*64 + d
  const int bh = bd >> 6;
  const int tid = threadIdx.x;
  const float* src = Vt + ((size_t)bd << 10);
  const float* vb = vv + (bh << 10);
  ushort* dst = Vpt + ((size_t)bd << 10);
  float s = 0.f;
  for (int t = tid; t < 1024; t += 256) {
    float p = src[t] * vb[t];
    s += p;
    dst[t] = f2bf(p);
  }
  for (int o = 32; o; o >>= 1) s += __shfl_down(s, o);
  __shared__ float red[4];
  if ((tid & 63) == 0) red[tid >> 6] = s;
  __syncthreads();
  if (tid == 0) Wd[bd] = red[0] + red[1] + red[2] + red[3];
}

// ------- y = 1024*u ⊙ (Wd - D @ V'), write [B][T][H*64+d] bf16 (triangular K) -------
__global__ __launch_bounds__(256) void gemm_pv_k(
    const ushort* __restrict__ SK, const ushort* __restrict__ Vpt,
    const float* __restrict__ u, const float* __restrict__ Wd,
    ushort* __restrict__ yb) {
  const int qt = blockIdx.y, bh = blockIdx.z;
  const int arow0 = qt * 64;
  const int brow0 = 0;
  const int kdim = (qt + 1) << 6;
  const ushort* A = SK + ((size_t)bh << 20);
  const ushort* B = Vpt + ((size_t)bh << 16);
  GEMM_PROLOG();
  GEMM_LOOP(A, B, 1024, 1024, kdim);
  const int bb = bh / 12, h = bh - bb * 12;
  GEMM_EPILOG({
    float yv = (Wd[(bh << 6) + gc] - val) * u[(bh << 10) + gr] * 1024.0f;
    yb[((size_t)((bb << 10) + gr)) * 768 + (h << 6) + gc] = f2bf(yv);
  });
}

// ------------------------------------------------------------------------------------
extern "C" void kernel_launch(void* const* d_in, const int* in_sizes, int n_in,
                              void* d_out, int out_size, void* d_ws, size_t ws_size,
                              hipStream_t stream) {
  const float* x      = (const float*)d_in[0];
  const float* ln_w   = (const float*)d_in[1];
  const float* ln_b   = (const float*)d_in[2];
  const float* W_attn = (const float*)d_in[3];
  const float* b_attn = (const float*)d_in[4];
  const float* W_proj = (const float*)d_in[5];
  const float* b_proj = (const float*)d_in[6];
  float* out = (float*)d_out;
  char* ws = (char*)d_ws;

  // ws layout (bytes); total ~150.3 MB
  ushort* xnb = (ushort*)(ws + 0);            // 4096*800 bf16
  ushort* WaT = (ushort*)(ws + 6553600);      // 2304*800 bf16
  ushort* WpT = (ushort*)(ws + 10240000);     // 768*768 bf16
  ushort* qb  = (ushort*)(ws + 11419648);     // 48*1024*64 bf16 (dead after gemm_s)
  ushort* kb  = (ushort*)(ws + 17711104);     // 48*1024*64 bf16 (dead after gemm_s)
  float*  Vt  = (float*) (ws + 24002560);     // 48*64*1024 f32 (d-major)
  ushort* SK  = (ushort*)(ws + 36585472);     // 48*1024*1024 bf16 (S, then D)
  ushort* Vpt = (ushort*)(ws + 137248768);    // 48*64*1024 bf16
  ushort* yb  = (ushort*)(ws + 143540224);    // 4096*768 bf16
  float*  u   = (float*) (ws + 149831680);    // 48*1024 f32
  float*  vv  = (float*) (ws + 150028288);    // 48*1024 f32
  float*  Wd  = (float*) (ws + 150224896);    // 48*64 f32
  // overlay on dead qb/kb region (after gemm_s):
  float*  colpart = (float*)(ws + 11419648);  // 32*48*1024 f32 = 6.29MB

  hipLaunchKernelGGL(ln_k, dim3(4096), dim3(256), 0, stream, x, ln_w, ln_b, xnb);
  hipLaunchKernelGGL(tr_k, dim3(72, 25), dim3(256), 0, stream, W_attn, WaT, 769, 2304, 800);
  hipLaunchKernelGGL(tr_k, dim3(24, 24), dim3(256), 0, stream, W_proj, WpT, 768, 768, 768);
  hipLaunchKernelGGL(gemm_qkv_k, dim3(18, 32), dim3(256), 0, stream,
                     xnb, WaT, b_attn, qb, kb, Vt);
  hipLaunchKernelGGL(gemm_s_k, dim3(16, 16, 48), dim3(256), 0, stream, qb, kb, SK);
  hipLaunchKernelGGL(kmat_k, dim3(12288), dim3(256), 0, stream, SK);
  hipLaunchKernelGGL(init_v_k, dim3(192), dim3(256), 0, stream, vv);
  for (int it = 0; it < 6; ++it) {
    hipLaunchKernelGGL(sink_k, dim3(16, 48), dim3(256), 0, stream, SK, vv, u, colpart);
    hipLaunchKernelGGL(vfin_k, dim3(4, 48), dim3(256), 0, stream, colpart, u, vv);
  }
  hipLaunchKernelGGL(vprep_k, dim3(3072), dim3(256), 0, stream, Vt, vv, Vpt, Wd);
  hipLaunchKernelGGL(gemm_pv_k, dim3(1, 16, 48), dim3(256), 0, stream, SK, Vpt, u, Wd, yb);
  hipLaunchKernelGGL(gemm_proj_k, dim3(6, 32), dim3(256), 0, stream, yb, WpT, b_proj, out);
}

// Round 7
// 317.048 us; speedup vs baseline: 3.2960x; 1.0086x over previous
//
#include <hip/hip_runtime.h>

typedef float f32x4 __attribute__((ext_vector_type(4)));
typedef float f32x2 __attribute__((ext_vector_type(2)));
typedef __bf16 bf16x8 __attribute__((ext_vector_type(8)));

#define MU (1.0f / 1024.0f)

__device__ __forceinline__ float bf2f(ushort u) {
  union { uint i; float f; } v; v.i = ((uint)u) << 16; return v.f;
}
__device__ __forceinline__ ushort f2bf(float f) {
  union { float f; uint i; } v; v.f = f;
  uint r = v.i + 0x7fffu + ((v.i >> 16) & 1u);  // RNE
  return (ushort)(r >> 16);
}
__device__ __forceinline__ void up8(uint4 v, float* o) {
  o[0] = bf2f((ushort)v.x); o[1] = bf2f((ushort)(v.x >> 16));
  o[2] = bf2f((ushort)v.y); o[3] = bf2f((ushort)(v.y >> 16));
  o[4] = bf2f((ushort)v.z); o[5] = bf2f((ushort)(v.z >> 16));
  o[6] = bf2f((ushort)v.w); o[7] = bf2f((ushort)(v.w >> 16));
}
__device__ __forceinline__ uint4 pk8(const float* f) {
  uint4 r;
  r.x = (uint)f2bf(f[0]) | ((uint)f2bf(f[1]) << 16);
  r.y = (uint)f2bf(f[2]) | ((uint)f2bf(f[3]) << 16);
  r.z = (uint)f2bf(f[4]) | ((uint)f2bf(f[5]) << 16);
  r.w = (uint)f2bf(f[6]) | ((uint)f2bf(f[7]) << 16);
  return r;
}
// unpack 8 bf16 -> 4 packed f32x2 (lo = u<<16, hi = u&0xffff0000)
__device__ __forceinline__ void up8p(uint4 v, f32x2* o) {
  union { uint i; float f; } a, b;
  a.i = v.x << 16; b.i = v.x & 0xffff0000u; o[0] = (f32x2){a.f, b.f};
  a.i = v.y << 16; b.i = v.y & 0xffff0000u; o[1] = (f32x2){a.f, b.f};
  a.i = v.z << 16; b.i = v.z & 0xffff0000u; o[2] = (f32x2){a.f, b.f};
  a.i = v.w << 16; b.i = v.w & 0xffff0000u; o[3] = (f32x2){a.f, b.f};
}
// packed dual f32 FMA: d = a*b + c (VOP3P)
__device__ __forceinline__ f32x2 pkfma(f32x2 a, f32x2 b, f32x2 c) {
  f32x2 d;
  asm("v_pk_fma_f32 %0, %1, %2, %3" : "=v"(d) : "v"(a), "v"(b), "v"(c));
  return d;
}

// async global->LDS, 16B per lane; lds base must be wave-uniform
typedef const __attribute__((address_space(1))) void gvoid;
typedef __attribute__((address_space(3))) void lvoid;
__device__ __forceinline__ void g2l16(const void* g, void* l) {
  __builtin_amdgcn_global_load_lds((gvoid*)g, (lvoid*)l, 16, 0, 0);
}

// ---------------- LayerNorm: x[4096][769] f32 -> xnb[4096][800] bf16 (zero-pad K) ---
__global__ __launch_bounds__(256) void ln_k(const float* __restrict__ x,
                                            const float* __restrict__ w,
                                            const float* __restrict__ b,
                                            ushort* __restrict__ xnb) {
  const int row = blockIdx.x;
  const int tid = threadIdx.x;
  const float* xr = x + (size_t)row * 769;
  float s = 0.f, ss = 0.f;
  for (int c = tid; c < 769; c += 256) { float v = xr[c]; s += v; ss += v * v; }
  for (int o = 32; o; o >>= 1) { s += __shfl_down(s, o); ss += __shfl_down(ss, o); }
  __shared__ float rs[4], rss[4];
  if ((tid & 63) == 0) { rs[tid >> 6] = s; rss[tid >> 6] = ss; }
  __syncthreads();
  s  = rs[0] + rs[1] + rs[2] + rs[3];
  ss = rss[0] + rss[1] + rss[2] + rss[3];
  const float mean = s * (1.0f / 769.0f);
  const float var  = ss * (1.0f / 769.0f) - mean * mean;
  const float rstd = rsqrtf(var + 1e-5f);
  ushort* orow = xnb + (size_t)row * 800;
  for (int c = tid; c < 800; c += 256) {
    float o = 0.f;
    if (c < 769) o = (xr[c] - mean) * rstd * w[c] + b[c];
    orow[c] = f2bf(o);
  }
}

// ---------------- transpose W[K][N] f32 -> Wt[N][Kp] bf16 (zero-pad K..Kp) ----------
__global__ __launch_bounds__(256) void tr_k(const float* __restrict__ W,
                                            ushort* __restrict__ Wt,
                                            int K, int N, int Kp) {
  __shared__ float ls[32][33];
  const int n0 = blockIdx.x * 32, k0 = blockIdx.y * 32;
  const int c = threadIdx.x & 31, r = threadIdx.x >> 5;  // r in 0..7
  for (int rr = 0; rr < 32; rr += 8) {
    int k = k0 + r + rr;
    ls[r + rr][c] = (k < K) ? W[(size_t)k * N + n0 + c] : 0.f;
  }
  __syncthreads();
  for (int rr = 0; rr < 32; rr += 8) {
    int n = n0 + r + rr;
    if (k0 + c < Kp) Wt[(size_t)n * Kp + k0 + c] = f2bf(ls[c][r + rr]);
  }
}

// ---------------- shared 64x64 GEMM core (used by gemm_s / gemm_pv) -----------------
#define GEMM_PROLOG() \
  __shared__ __align__(16) ushort lsA[64 * 40]; \
  __shared__ __align__(16) ushort lsB[64 * 40]; \
  const int tid = threadIdx.x; \
  const int lane = tid & 63; \
  const int wid = tid >> 6; \
  const int wr = wid >> 1, wc = wid & 1; \
  const int l15 = lane & 15, l4 = lane >> 4; \
  const int srow = tid >> 2, scol = (tid & 3) << 3; \
  f32x4 acc00 = {0.f, 0.f, 0.f, 0.f}; \
  f32x4 acc01 = acc00, acc10 = acc00, acc11 = acc00;

#define GEMM_LOOP(Aptr, Btptr, lda, ldb, kdim) \
  { const size_t aoff0 = (size_t)(arow0 + srow) * (lda) + scol; \
    const size_t boff0 = (size_t)(brow0 + srow) * (ldb) + scol; \
    for (int k0 = 0; k0 < (kdim); k0 += 32) { \
      uint4 av = *(const uint4*)((Aptr) + aoff0 + k0); \
      uint4 bv = *(const uint4*)((Btptr) + boff0 + k0); \
      __syncthreads(); \
      *(uint4*)(lsA + srow * 40 + scol) = av; \
      *(uint4*)(lsB + srow * 40 + scol) = bv; \
      __syncthreads(); \
      bf16x8 af0 = *(const bf16x8*)(lsA + (wr * 32 + l15) * 40 + l4 * 8); \
      bf16x8 af1 = *(const bf16x8*)(lsA + (wr * 32 + 16 + l15) * 40 + l4 * 8); \
      bf16x8 bq0 = *(const bf16x8*)(lsB + (wc * 32 + l15) * 40 + l4 * 8); \
      bf16x8 bq1 = *(const bf16x8*)(lsB + (wc * 32 + 16 + l15) * 40 + l4 * 8); \
      acc00 = __builtin_amdgcn_mfma_f32_16x16x32_bf16(af0, bq0, acc00, 0, 0, 0); \
      acc01 = __builtin_amdgcn_mfma_f32_16x16x32_bf16(af0, bq1, acc01, 0, 0, 0); \
      acc10 = __builtin_amdgcn_mfma_f32_16x16x32_bf16(af1, bq0, acc10, 0, 0, 0); \
      acc11 = __builtin_amdgcn_mfma_f32_16x16x32_bf16(af1, bq1, acc11, 0, 0, 0); \
    } }

#define EPI_ONE(ACC, FM, FN, ...) \
  { _Pragma("unroll") for (int r = 0; r < 4; ++r) { \
      int gr = arow0 + wr * 32 + (FM) * 16 + l4 * 4 + r; \
      int gc = brow0 + wc * 32 + (FN) * 16 + l15; \
      float val = ACC[r]; \
      __VA_ARGS__; \
  } }
#define GEMM_EPILOG(...) \
  EPI_ONE(acc00, 0, 0, __VA_ARGS__) EPI_ONE(acc01, 0, 1, __VA_ARGS__) \
  EPI_ONE(acc10, 1, 0, __VA_ARGS__) EPI_ONE(acc11, 1, 1, __VA_ARGS__)

// -------- 128x128 tile, 2-phase double-buffered, BK=32 ------------------------------
#define TILE128_PROLOG() \
  __shared__ __align__(16) ushort lsA[2][128 * 32]; \
  __shared__ __align__(16) ushort lsB[2][128 * 32]; \
  const int tid = threadIdx.x, lane = tid & 63, w = tid >> 6; \
  const int wr = w >> 1, wc = w & 1; \
  const int l15 = lane & 15, l4 = lane >> 4; \
  const int scol = (lane & 3) * 8; \
  const int srow = lane >> 2; \
  f32x4 acc[4][4]; \
  _Pragma("unroll") for (int m = 0; m < 4; ++m) \
    _Pragma("unroll") for (int n = 0; n < 4; ++n) acc[m][n] = (f32x4){0.f, 0.f, 0.f, 0.f};

#define TILE128_LOOP(Aptr, Btptr, lda, ldb, kdim) { \
  const ushort* ga0 = (Aptr) + (size_t)(arow0 + w * 32 + srow) * (lda) + scol; \
  const ushort* ga1 = ga0 + 16 * (lda); \
  const ushort* gb0 = (Btptr) + (size_t)(brow0 + w * 32 + srow) * (ldb) + scol; \
  const ushort* gb1 = gb0 + 16 * (ldb); \
  g2l16(ga0, &lsA[0][(w * 2) * 512]); \
  g2l16(ga1, &lsA[0][(w * 2 + 1) * 512]); \
  g2l16(gb0, &lsB[0][(w * 2) * 512]); \
  g2l16(gb1, &lsB[0][(w * 2 + 1) * 512]); \
  __syncthreads(); \
  int cur = 0; \
  for (int k0 = 0; k0 < (kdim); k0 += 32) { \
    if (k0 + 32 < (kdim)) { \
      g2l16(ga0 + k0 + 32, &lsA[cur ^ 1][(w * 2) * 512]); \
      g2l16(ga1 + k0 + 32, &lsA[cur ^ 1][(w * 2 + 1) * 512]); \
      g2l16(gb0 + k0 + 32, &lsB[cur ^ 1][(w * 2) * 512]); \
      g2l16(gb1 + k0 + 32, &lsB[cur ^ 1][(w * 2 + 1) * 512]); \
    } \
    bf16x8 af[4], bq[4]; \
    _Pragma("unroll") for (int m = 0; m < 4; ++m) \
      af[m] = *(const bf16x8*)(&lsA[cur][(wr * 64 + m * 16 + l15) * 32 + l4 * 8]); \
    _Pragma("unroll") for (int n = 0; n < 4; ++n) \
      bq[n] = *(const bf16x8*)(&lsB[cur][(wc * 64 + n * 16 + l15) * 32 + l4 * 8]); \
    _Pragma("unroll") for (int m = 0; m < 4; ++m) \
      _Pragma("unroll") for (int n = 0; n < 4; ++n) \
        acc[m][n] = __builtin_amdgcn_mfma_f32_16x16x32_bf16(af[m], bq[n], acc[m][n], 0, 0, 0); \
    __syncthreads(); \
    cur ^= 1; \
  } }

// ------- QKV GEMM, 128x128 tile 2-phase; grid (18, 32) ------------------------------
__global__ __launch_bounds__(256) void gemm_qkv_k(
    const ushort* __restrict__ xnb, const ushort* __restrict__ WaT,
    const float* __restrict__ b_attn,
    ushort* __restrict__ qb, ushort* __restrict__ kb, float* __restrict__ Vt) {
  const int arow0 = blockIdx.y * 128, brow0 = blockIdx.x * 128;
  TILE128_PROLOG();
  TILE128_LOOP(xnb, WaT, 800, 800, 800);
#pragma unroll
  for (int m = 0; m < 4; ++m)
#pragma unroll
    for (int n = 0; n < 4; ++n) {
      const int gc = brow0 + wc * 64 + n * 16 + l15;
      const float bias = b_attn[gc];
      const int sect = gc / 768;
      const int e = gc - sect * 768;
      const int h = e >> 6;
      const int d = e & 63;
#pragma unroll
      for (int r = 0; r < 4; ++r) {
        const int gr = arow0 + wr * 64 + m * 16 + l4 * 4 + r;
        const int bb = gr >> 10;
        const int t = gr & 1023;
        const size_t bh = (size_t)(bb * 12 + h);
        const float val = acc[m][n][r] + bias;
        if (sect == 0)      qb[(bh << 16) + ((size_t)t << 6) + d] = f2bf(val * 0.125f);
        else if (sect == 1) kb[(bh << 16) + ((size_t)t << 6) + d] = f2bf(val);
        else                Vt[(bh << 16) + ((size_t)d << 10) + t] = val;
      }
    }
}

// ------- proj GEMM: out = yb[4096][768] @ WpT[768][768]^T + b, 128x128 2-phase ------
__global__ __launch_bounds__(256) void gemm_proj_k(
    const ushort* __restrict__ yb, const ushort* __restrict__ WpT,
    const float* __restrict__ b_proj, float* __restrict__ out) {
  const int arow0 = blockIdx.y * 128, brow0 = blockIdx.x * 128;
  TILE128_PROLOG();
  TILE128_LOOP(yb, WpT, 768, 768, 768);
#pragma unroll
  for (int m = 0; m < 4; ++m)
#pragma unroll
    for (int n = 0; n < 4; ++n) {
      const int gc = brow0 + wc * 64 + n * 16 + l15;
      const float bias = b_proj[gc];
#pragma unroll
      for (int r = 0; r < 4; ++r) {
        const int gr = arow0 + wr * 64 + m * 16 + l4 * 4 + r;
        out[(size_t)gr * 768 + gc] = acc[m][n][r] + bias;
      }
    }
}

// ---------------- S = q k^T per (b,h): heavy q-tiles dispatched first ---------------
__global__ __launch_bounds__(256) void gemm_s_k(
    const ushort* __restrict__ qb, const ushort* __restrict__ kb,
    ushort* __restrict__ SK) {
  const int kt = blockIdx.x, qt = 15 - blockIdx.y, bh = blockIdx.z;
  if (kt > qt) return;  // strictly above diagonal: never read
  const int arow0 = qt * 64;
  const int brow0 = kt * 64;
  const ushort* A = qb + ((size_t)bh << 16);
  const ushort* B = kb + ((size_t)bh << 16);
  ushort* S = SK + ((size_t)bh << 20);
  GEMM_PROLOG();
  GEMM_LOOP(A, B, 64, 64, 64);
  GEMM_EPILOG({ S[((size_t)gr << 10) + gc] = f2bf(val); });
}

// ---- FUSED: row softmax -> D = 1-exp(-p) in place (band write) -> Sinkhorn iter 1 --
// v0 = 1, sv = 1024: u1_i = MU/(1024 - sum_j D_ij); colacc += u1_i * D_i.
// grid (32 stripe-pairs, 48 bh); 4 waves; 16-row stripes (heavy 63-p + light p).
__global__ __launch_bounds__(256) void kmat_k(ushort* __restrict__ SK,
                                              float* __restrict__ u,
                                              float* __restrict__ colpart) {
  const int pair = blockIdx.x, bh = blockIdx.y;
  const int tid = threadIdx.x, lane = tid & 63, w = tid >> 6;
  ushort* base = SK + ((size_t)bh << 20);
  const int cA = lane, cB = lane + 64;
  __shared__ float cred[4][1024];
  uint4 z4 = make_uint4(0, 0, 0, 0);
  for (int half = 0; half < 2; ++half) {
    const int stripe = half ? pair : (63 - pair);
    const int rstart = stripe * 16 + w * 4;
    float ca[16];
#pragma unroll
    for (int e = 0; e < 16; ++e) ca[e] = 0.f;
    for (int r = 0; r < 4; ++r) {
      const int i = rstart + r;
      ushort* row = base + ((size_t)i << 10);
      const int nc8 = i >> 3;
      uint4 da = (cA <= nc8) ? *(const uint4*)(row + 8 * cA) : z4;
      uint4 db = (cB <= nc8) ? *(const uint4*)(row + 8 * cB) : z4;
      float xa[8], xb[8];
      up8(da, xa); up8(db, xb);
      float m = -1e30f;
#pragma unroll
      for (int e = 0; e < 8; ++e) {
        if (8 * cA + e <= i) m = fmaxf(m, xa[e]);
        if (8 * cB + e <= i) m = fmaxf(m, xb[e]);
      }
#pragma unroll
      for (int o = 1; o < 64; o <<= 1) m = fmaxf(m, __shfl_xor(m, o));
      float pa[8], pb[8];
      float s = 0.f;
#pragma unroll
      for (int e = 0; e < 8; ++e) {
        pa[e] = (8 * cA + e <= i) ? __expf(xa[e] - m) : 0.f;
        pb[e] = (8 * cB + e <= i) ? __expf(xb[e] - m) : 0.f;
        s += pa[e] + pb[e];
      }
#pragma unroll
      for (int o = 1; o < 64; o <<= 1) s += __shfl_xor(s, o);
      const float inv = 1.0f / s;
      float Da[8], Db[8];
      float rs = 0.f;
#pragma unroll
      for (int e = 0; e < 8; ++e) {
        Da[e] = (8 * cA + e <= i) ? (1.0f - __expf(-pa[e] * inv)) : 0.f;
        Db[e] = (8 * cB + e <= i) ? (1.0f - __expf(-pb[e] * inv)) : 0.f;
        rs += Da[e] + Db[e];
      }
#pragma unroll
      for (int o = 1; o < 64; o <<= 1) rs += __shfl_xor(rs, o);
      const float ui = MU / (1024.0f - rs);
      if (lane == 0) u[(bh << 10) + i] = ui;
      const int bandc = ((i >> 6) + 1) << 3;
      if (cA < bandc) *(uint4*)(row + 8 * cA) = pk8(Da);
      if (cB < bandc) *(uint4*)(row + 8 * cB) = pk8(Db);
#pragma unroll
      for (int e = 0; e < 8; ++e) { ca[e] += ui * Da[e]; ca[8 + e] += ui * Db[e]; }
    }
    if (half) __syncthreads();
#pragma unroll
    for (int e = 0; e < 16; ++e) cred[w][e * 64 + lane] = ca[e];
    __syncthreads();
    float* cp = colpart + (((size_t)stripe * 48 + bh) << 10);
#pragma unroll
    for (int pp = 0; pp < 4; ++pp) {
      int p = tid + pp * 256;
      cp[p] = cred[0][p] + cred[1][p] + cred[2][p] + cred[3][p];
    }
  }
}

// ------ fused Sinkhorn half-sweep (iters 2..6): u_i = MU/(sv - D_i·v); colacc -------
// grid (32 stripe-pairs, 48 bh); 16-row stripes; packed f32 FMA inner loop.
__global__ __launch_bounds__(256) void sink_k(
    const ushort* __restrict__ SK, const float* __restrict__ vv,
    float* __restrict__ u, float* __restrict__ colpart) {
  const int pair = blockIdx.x, bh = blockIdx.y;
  const int tid = threadIdx.x, lane = tid & 63, w = tid >> 6;
  const ushort* base = SK + ((size_t)bh << 20);
  const f32x2* vb2 = (const f32x2*)(vv + (bh << 10));
  f32x2 vr2[8];
#pragma unroll
  for (int e2 = 0; e2 < 4; ++e2) {
    vr2[e2]     = vb2[4 * lane + e2];
    vr2[4 + e2] = vb2[256 + 4 * lane + e2];
  }
  float sv = 0.f;
#pragma unroll
  for (int e2 = 0; e2 < 8; ++e2) sv += vr2[e2].x + vr2[e2].y;
#pragma unroll
  for (int o = 1; o < 64; o <<= 1) sv += __shfl_xor(sv, o);
  __shared__ float cred[4][1024];
  uint4 z4 = make_uint4(0, 0, 0, 0);
  for (int half = 0; half < 2; ++half) {
    const int stripe = half ? pair : (63 - pair);
    const int rstart = stripe * 16 + w * 4;
    f32x2 ca2[8];
#pragma unroll
    for (int e2 = 0; e2 < 8; ++e2) ca2[e2] = (f32x2){0.f, 0.f};
    for (int r = 0; r < 4; ++r) {
      const int i = rstart + r;
      const ushort* row = base + ((size_t)i << 10);
      const int nc8 = i >> 3;
      uint4 da = (lane <= nc8)      ? *(const uint4*)(row + 8 * lane)       : z4;
      uint4 db = (lane + 64 <= nc8) ? *(const uint4*)(row + 512 + 8 * lane) : z4;
      f32x2 d2[8];
      up8p(da, d2); up8p(db, d2 + 4);
      f32x2 acc2 = (f32x2){0.f, 0.f};
#pragma unroll
      for (int e2 = 0; e2 < 8; ++e2) acc2 = pkfma(d2[e2], vr2[e2], acc2);
      float a = acc2.x + acc2.y;
#pragma unroll
      for (int o = 1; o < 64; o <<= 1) a += __shfl_xor(a, o);
      const float ui = MU / (sv - a);
      if (lane == 0) u[(bh << 10) + i] = ui;
      const f32x2 uu = (f32x2){ui, ui};
#pragma unroll
      for (int e2 = 0; e2 < 8; ++e2) ca2[e2] = pkfma(uu, d2[e2], ca2[e2]);
    }
    if (half) __syncthreads();
    const float* caf = (const float*)ca2;
#pragma unroll
    for (int e = 0; e < 16; ++e) cred[w][e * 64 + lane] = caf[e];
    __syncthreads();
    float* cp = colpart + (((size_t)stripe * 48 + bh) << 10);
#pragma unroll
    for (int pp = 0; pp < 4; ++pp) {
      int p = tid + pp * 256;
      cp[p] = cred[0][p] + cred[1][p] + cred[2][p] + cred[3][p];
    }
  }
}

// ------ finish v-update: v_j = MU/(su - colsum_j). grid (4 col-chunks, 48 bh) -------
__global__ __launch_bounds__(256) void vfin_k(
    const float* __restrict__ colpart, const float* __restrict__ u,
    float* __restrict__ vv) {
  const int cq = blockIdx.x, bh = blockIdx.y;
  const int tid = threadIdx.x;
  float su = 0.f;
  for (int t = tid; t < 1024; t += 256) su += u[(bh << 10) + t];
#pragma unroll
  for (int o = 1; o < 64; o <<= 1) su += __shfl_xor(su, o);
  __shared__ float red[4];
  if ((tid & 63) == 0) red[tid >> 6] = su;
  __syncthreads();
  su = red[0] + red[1] + red[2] + red[3];
  const int c = cq * 256 + tid;
  int p;
  if (c < 512) p = (c & 7) * 64 + (c >> 3);
  else         p = (8 + ((c - 512) & 7)) * 64 + ((c - 512) >> 3);
  float s = 0.f;
  for (int st = 0; st < 64; ++st)
    s += colpart[(((size_t)st * 48 + bh) << 10) + p];
  vv[(bh << 10) + c] = MU / (su - s);
}

// ---------------- V' = v ⊙ V (bf16, d-major) + Wd[bh][d] = sum_t V'[t][d] -----------
__global__ __launch_bounds__(256) void vprep_k(const float* __restrict__ Vt,
                                               const float* __restrict__ vv,
                                               ushort* __restrict__ Vpt,
                                               float* __restrict__ Wd) {
  const int bd = blockIdx.x;            // bh*64 + d
  const int bh = bd >> 6;
  const int tid = threadIdx.x;
  const float* src = Vt + ((size_t)bd << 10);
  const float* vb = vv + (bh << 10);
  ushort* dst = Vpt + ((size_t)bd << 10);
  float s = 0.f;
  for (int t = tid; t < 1024; t += 256) {
    float p = src[t] * vb[t];
    s += p;
    dst[t] = f2bf(p);
  }
  for (int o = 32; o; o >>= 1) s += __shfl_down(s, o);
  __shared__ float red[4];
  if ((tid & 63) == 0) red[tid >> 6] = s;
  __syncthreads();
  if (tid == 0) Wd[bd] = red[0] + red[1] + red[2] + red[3];
}

// ------- y = 1024*u ⊙ (Wd - D @ V'), heavy q-tiles first (triangular K) -------------
__global__ __launch_bounds__(256) void gemm_pv_k(
    const ushort* __restrict__ SK, const ushort* __restrict__ Vpt,
    const float* __restrict__ u, const float* __restrict__ Wd,
    ushort* __restrict__ yb) {
  const int qt = 15 - blockIdx.y, bh = blockIdx.z;
  const int arow0 = qt * 64;
  const int brow0 = 0;
  const int kdim = (qt + 1) << 6;
  const ushort* A = SK + ((size_t)bh << 20);
  const ushort* B = Vpt + ((size_t)bh << 16);
  GEMM_PROLOG();
  GEMM_LOOP(A, B, 1024, 1024, kdim);
  const int bb = bh / 12, h = bh - bb * 12;
  GEMM_EPILOG({
    float yv = (Wd[(bh << 6) + gc] - val) * u[(bh << 10) + gr] * 1024.0f;
    yb[((size_t)((bb << 10) + gr)) * 768 + (h << 6) + gc] = f2bf(yv);
  });
}

// ------------------------------------------------------------------------------------
extern "C" void kernel_launch(void* const* d_in, const int* in_sizes, int n_in,
                              void* d_out, int out_size, void* d_ws, size_t ws_size,
                              hipStream_t stream) {
  const float* x      = (const float*)d_in[0];
  const float* ln_w   = (const float*)d_in[1];
  const float* ln_b   = (const float*)d_in[2];
  const float* W_attn = (const float*)d_in[3];
  const float* b_attn = (const float*)d_in[4];
  const float* W_proj = (const float*)d_in[5];
  const float* b_proj = (const float*)d_in[6];
  float* out = (float*)d_out;
  char* ws = (char*)d_ws;

  // ws layout (bytes); total ~150.3 MB
  ushort* xnb = (ushort*)(ws + 0);            // 4096*800 bf16
  ushort* WaT = (ushort*)(ws + 6553600);      // 2304*800 bf16
  ushort* WpT = (ushort*)(ws + 10240000);     // 768*768 bf16
  ushort* qb  = (ushort*)(ws + 11419648);     // 48*1024*64 bf16 (dead after gemm_s)
  ushort* kb  = (ushort*)(ws + 17711104);     // 48*1024*64 bf16 (dead after gemm_s)
  float*  Vt  = (float*) (ws + 24002560);     // 48*64*1024 f32 (d-major)
  ushort* SK  = (ushort*)(ws + 36585472);     // 48*1024*1024 bf16 (S, then D)
  ushort* Vpt = (ushort*)(ws + 137248768);    // 48*64*1024 bf16
  ushort* yb  = (ushort*)(ws + 143540224);    // 4096*768 bf16
  float*  u   = (float*) (ws + 149831680);    // 48*1024 f32
  float*  vv  = (float*) (ws + 150028288);    // 48*1024 f32
  float*  Wd  = (float*) (ws + 150224896);    // 48*64 f32
  // overlay on dead qb/kb region (after gemm_s): 64*48*1024 f32 = 12.58 MB
  float*  colpart = (float*)(ws + 11419648);

  hipLaunchKernelGGL(ln_k, dim3(4096), dim3(256), 0, stream, x, ln_w, ln_b, xnb);
  hipLaunchKernelGGL(tr_k, dim3(72, 25), dim3(256), 0, stream, W_attn, WaT, 769, 2304, 800);
  hipLaunchKernelGGL(tr_k, dim3(24, 24), dim3(256), 0, stream, W_proj, WpT, 768, 768, 768);
  hipLaunchKernelGGL(gemm_qkv_k, dim3(18, 32), dim3(256), 0, stream,
                     xnb, WaT, b_attn, qb, kb, Vt);
  hipLaunchKernelGGL(gemm_s_k, dim3(16, 16, 48), dim3(256), 0, stream, qb, kb, SK);
  // fused softmax+D+Sinkhorn-iter-1 (u1 + colpart), then v1
  hipLaunchKernelGGL(kmat_k, dim3(32, 48), dim3(256), 0, stream, SK, u, colpart);
  hipLaunchKernelGGL(vfin_k, dim3(4, 48), dim3(256), 0, stream, colpart, u, vv);
  for (int it = 0; it < 5; ++it) {
    hipLaunchKernelGGL(sink_k, dim3(32, 48), dim3(256), 0, stream, SK, vv, u, colpart);
    hipLaunchKernelGGL(vfin_k, dim3(4, 48), dim3(256), 0, stream, colpart, u, vv);
  }
  hipLaunchKernelGGL(vprep_k, dim3(3072), dim3(256), 0, stream, Vt, vv, Vpt, Wd);
  hipLaunchKernelGGL(gemm_pv_k, dim3(1, 16, 48), dim3(256), 0, stream, SK, Vpt, u, Wd, yb);
  hipLaunchKernelGGL(gemm_proj_k, dim3(6, 32), dim3(256), 0, stream, yb, WpT, b_proj, out);
}

// Round 9
// 311.068 us; speedup vs baseline: 3.3594x; 1.0192x over previous
//
#include <hip/hip_runtime.h>

typedef float f32x4 __attribute__((ext_vector_type(4)));
typedef float f32x2 __attribute__((ext_vector_type(2)));
typedef __bf16 bf16x8 __attribute__((ext_vector_type(8)));

#define MU (1.0f / 1024.0f)

__device__ __forceinline__ float bf2f(ushort u) {
  union { uint i; float f; } v; v.i = ((uint)u) << 16; return v.f;
}
__device__ __forceinline__ ushort f2bf(float f) {
  union { float f; uint i; } v; v.f = f;
  uint r = v.i + 0x7fffu + ((v.i >> 16) & 1u);  // RNE
  return (ushort)(r >> 16);
}
__device__ __forceinline__ void up8(uint4 v, float* o) {
  o[0] = bf2f((ushort)v.x); o[1] = bf2f((ushort)(v.x >> 16));
  o[2] = bf2f((ushort)v.y); o[3] = bf2f((ushort)(v.y >> 16));
  o[4] = bf2f((ushort)v.z); o[5] = bf2f((ushort)(v.z >> 16));
  o[6] = bf2f((ushort)v.w); o[7] = bf2f((ushort)(v.w >> 16));
}
__device__ __forceinline__ uint4 pk8(const float* f) {
  uint4 r;
  r.x = (uint)f2bf(f[0]) | ((uint)f2bf(f[1]) << 16);
  r.y = (uint)f2bf(f[2]) | ((uint)f2bf(f[3]) << 16);
  r.z = (uint)f2bf(f[4]) | ((uint)f2bf(f[5]) << 16);
  r.w = (uint)f2bf(f[6]) | ((uint)f2bf(f[7]) << 16);
  return r;
}
// unpack 8 bf16 -> 4 packed f32x2
__device__ __forceinline__ void up8p(uint4 v, f32x2* o) {
  union { uint i; float f; } a, b;
  a.i = v.x << 16; b.i = v.x & 0xffff0000u; o[0] = (f32x2){a.f, b.f};
  a.i = v.y << 16; b.i = v.y & 0xffff0000u; o[1] = (f32x2){a.f, b.f};
  a.i = v.z << 16; b.i = v.z & 0xffff0000u; o[2] = (f32x2){a.f, b.f};
  a.i = v.w << 16; b.i = v.w & 0xffff0000u; o[3] = (f32x2){a.f, b.f};
}
__device__ __forceinline__ f32x2 pkfma(f32x2 a, f32x2 b, f32x2 c) {
  f32x2 d;
  asm("v_pk_fma_f32 %0, %1, %2, %3" : "=v"(d) : "v"(a), "v"(b), "v"(c));
  return d;
}
__device__ __forceinline__ int permcol(int c) {
  return (c < 512) ? ((c & 7) * 64 + (c >> 3))
                   : ((8 + ((c - 512) & 7)) * 64 + ((c - 512) >> 3));
}

// async global->LDS, 16B per lane; lds base must be wave-uniform
typedef const __attribute__((address_space(1))) void gvoid;
typedef __attribute__((address_space(3))) void lvoid;
__device__ __forceinline__ void g2l16(const void* g, void* l) {
  __builtin_amdgcn_global_load_lds((gvoid*)g, (lvoid*)l, 16, 0, 0);
}

// ---------------- LayerNorm: x[4096][769] f32 -> xnb[4096][832] bf16 (zero-pad K) ---
__global__ __launch_bounds__(256) void ln_k(const float* __restrict__ x,
                                            const float* __restrict__ w,
                                            const float* __restrict__ b,
                                            ushort* __restrict__ xnb) {
  const int row = blockIdx.x;
  const int tid = threadIdx.x;
  const float* xr = x + (size_t)row * 769;
  float s = 0.f, ss = 0.f;
  for (int c = tid; c < 769; c += 256) { float v = xr[c]; s += v; ss += v * v; }
  for (int o = 32; o; o >>= 1) { s += __shfl_down(s, o); ss += __shfl_down(ss, o); }
  __shared__ float rs[4], rss[4];
  if ((tid & 63) == 0) { rs[tid >> 6] = s; rss[tid >> 6] = ss; }
  __syncthreads();
  s  = rs[0] + rs[1] + rs[2] + rs[3];
  ss = rss[0] + rss[1] + rss[2] + rss[3];
  const float mean = s * (1.0f / 769.0f);
  const float var  = ss * (1.0f / 769.0f) - mean * mean;
  const float rstd = rsqrtf(var + 1e-5f);
  ushort* orow = xnb + (size_t)row * 832;
  for (int c = tid; c < 832; c += 256) {
    float o = 0.f;
    if (c < 769) o = (xr[c] - mean) * rstd * w[c] + b[c];
    orow[c] = f2bf(o);
  }
}

// ---------------- transpose W[K][N] f32 -> Wt[N][Kp] bf16 (zero-pad K..Kp) ----------
__global__ __launch_bounds__(256) void tr_k(const float* __restrict__ W,
                                            ushort* __restrict__ Wt,
                                            int K, int N, int Kp) {
  __shared__ float ls[32][33];
  const int n0 = blockIdx.x * 32, k0 = blockIdx.y * 32;
  const int c = threadIdx.x & 31, r = threadIdx.x >> 5;  // r in 0..7
  for (int rr = 0; rr < 32; rr += 8) {
    int k = k0 + r + rr;
    ls[r + rr][c] = (k < K) ? W[(size_t)k * N + n0 + c] : 0.f;
  }
  __syncthreads();
  for (int rr = 0; rr < 32; rr += 8) {
    int n = n0 + r + rr;
    if (k0 + c < Kp) Wt[(size_t)n * Kp + k0 + c] = f2bf(ls[c][r + rr]);
  }
}

// ---------------- shared 64x64 GEMM core (used by gemm_s / gemm_pv) -----------------
#define GEMM_PROLOG() \
  __shared__ __align__(16) ushort lsA[64 * 40]; \
  __shared__ __align__(16) ushort lsB[64 * 40]; \
  const int tid = threadIdx.x; \
  const int lane = tid & 63; \
  const int wid = tid >> 6; \
  const int wr = wid >> 1, wc = wid & 1; \
  const int l15 = lane & 15, l4 = lane >> 4; \
  const int srow = tid >> 2, scol = (tid & 3) << 3; \
  f32x4 acc00 = {0.f, 0.f, 0.f, 0.f}; \
  f32x4 acc01 = acc00, acc10 = acc00, acc11 = acc00;

#define GEMM_LOOP(Aptr, Btptr, lda, ldb, kdim) \
  { const size_t aoff0 = (size_t)(arow0 + srow) * (lda) + scol; \
    const size_t boff0 = (size_t)(brow0 + srow) * (ldb) + scol; \
    for (int k0 = 0; k0 < (kdim); k0 += 32) { \
      uint4 av = *(const uint4*)((Aptr) + aoff0 + k0); \
      uint4 bv = *(const uint4*)((Btptr) + boff0 + k0); \
      __syncthreads(); \
      *(uint4*)(lsA + srow * 40 + scol) = av; \
      *(uint4*)(lsB + srow * 40 + scol) = bv; \
      __syncthreads(); \
      bf16x8 af0 = *(const bf16x8*)(lsA + (wr * 32 + l15) * 40 + l4 * 8); \
      bf16x8 af1 = *(const bf16x8*)(lsA + (wr * 32 + 16 + l15) * 40 + l4 * 8); \
      bf16x8 bq0 = *(const bf16x8*)(lsB + (wc * 32 + l15) * 40 + l4 * 8); \
      bf16x8 bq1 = *(const bf16x8*)(lsB + (wc * 32 + 16 + l15) * 40 + l4 * 8); \
      acc00 = __builtin_amdgcn_mfma_f32_16x16x32_bf16(af0, bq0, acc00, 0, 0, 0); \
      acc01 = __builtin_amdgcn_mfma_f32_16x16x32_bf16(af0, bq1, acc01, 0, 0, 0); \
      acc10 = __builtin_amdgcn_mfma_f32_16x16x32_bf16(af1, bq0, acc10, 0, 0, 0); \
      acc11 = __builtin_amdgcn_mfma_f32_16x16x32_bf16(af1, bq1, acc11, 0, 0, 0); \
    } }

#define EPI_ONE(ACC, FM, FN, ...) \
  { _Pragma("unroll") for (int r = 0; r < 4; ++r) { \
      int gr = arow0 + wr * 32 + (FM) * 16 + l4 * 4 + r; \
      int gc = brow0 + wc * 32 + (FN) * 16 + l15; \
      float val = ACC[r]; \
      __VA_ARGS__; \
  } }
#define GEMM_EPILOG(...) \
  EPI_ONE(acc00, 0, 0, __VA_ARGS__) EPI_ONE(acc01, 0, 1, __VA_ARGS__) \
  EPI_ONE(acc10, 1, 0, __VA_ARGS__) EPI_ONE(acc11, 1, 1, __VA_ARGS__)

// ------- QKV GEMM, 128x128 tile, BK=64, 2-phase dbuf, XOR-swizzled LDS --------------
__global__ __launch_bounds__(256) void gemm_qkv_k(
    const ushort* __restrict__ xnb, const ushort* __restrict__ WaT,
    const float* __restrict__ b_attn,
    ushort* __restrict__ qb, ushort* __restrict__ kb, float* __restrict__ Vt) {
  __shared__ __align__(16) ushort lsA[2][128 * 64];
  __shared__ __align__(16) ushort lsB[2][128 * 64];
  const int tid = threadIdx.x, lane = tid & 63, w = tid >> 6;
  const int wr = w >> 1, wc = w & 1;
  const int l15 = lane & 15, l4 = lane >> 4;
  const int arow0 = blockIdx.y * 128, brow0 = blockIdx.x * 128;
  f32x4 acc[4][4];
#pragma unroll
  for (int m = 0; m < 4; ++m)
#pragma unroll
    for (int n = 0; n < 4; ++n) acc[m][n] = (f32x4){0.f, 0.f, 0.f, 0.f};

  const int srow = (lane >> 3);
  const int scol16 = ((lane & 7) ^ srow) * 8;   // pre-swizzled source chunk
  const ushort* gA = xnb + (size_t)(arow0 + w * 32 + srow) * 832 + scol16;
  const ushort* gB = WaT + (size_t)(brow0 + w * 32 + srow) * 832 + scol16;

#define QKV_STAGE(buf, k0) { \
  _Pragma("unroll") for (int s = 0; s < 4; ++s) { \
    g2l16(gA + (size_t)(s * 8) * 832 + (k0), &lsA[buf][(w * 32 + s * 8) * 64]); \
    g2l16(gB + (size_t)(s * 8) * 832 + (k0), &lsB[buf][(w * 32 + s * 8) * 64]); \
  } }

  QKV_STAGE(0, 0);
  __syncthreads();
  int cur = 0;
  for (int k0 = 0; k0 < 832; k0 += 64) {
    if (k0 + 64 < 832) QKV_STAGE(cur ^ 1, k0 + 64);
    bf16x8 af[2][4], bq[2][4];
#pragma unroll
    for (int kk = 0; kk < 2; ++kk) {
#pragma unroll
      for (int m = 0; m < 4; ++m) {
        const int r = wr * 64 + m * 16 + l15;
        af[kk][m] = *(const bf16x8*)(&lsA[cur][r * 64 + (((kk * 4 + l4) ^ (l15 & 7)) * 8)]);
      }
#pragma unroll
      for (int n = 0; n < 4; ++n) {
        const int r = wc * 64 + n * 16 + l15;
        bq[kk][n] = *(const bf16x8*)(&lsB[cur][r * 64 + (((kk * 4 + l4) ^ (l15 & 7)) * 8)]);
      }
    }
#pragma unroll
    for (int kk = 0; kk < 2; ++kk)
#pragma unroll
      for (int m = 0; m < 4; ++m)
#pragma unroll
        for (int n = 0; n < 4; ++n)
          acc[m][n] = __builtin_amdgcn_mfma_f32_16x16x32_bf16(af[kk][m], bq[kk][n], acc[m][n], 0, 0, 0);
    __syncthreads();
    cur ^= 1;
  }

#pragma unroll
  for (int m = 0; m < 4; ++m)
#pragma unroll
    for (int n = 0; n < 4; ++n) {
      const int gc = brow0 + wc * 64 + n * 16 + l15;
      const float bias = b_attn[gc];
      const int sect = gc / 768;
      const int e = gc - sect * 768;
      const int h = e >> 6;
      const int d = e & 63;
#pragma unroll
      for (int r = 0; r < 4; ++r) {
        const int gr = arow0 + wr * 64 + m * 16 + l4 * 4 + r;
        const int bb = gr >> 10;
        const int t = gr & 1023;
        const size_t bh = (size_t)(bb * 12 + h);
        const float val = acc[m][n][r] + bias;
        if (sect == 0)      qb[(bh << 16) + ((size_t)t << 6) + d] = f2bf(val * 0.125f);
        else if (sect == 1) kb[(bh << 16) + ((size_t)t << 6) + d] = f2bf(val);
        else                Vt[(bh << 16) + ((size_t)d << 10) + t] = val;
      }
    }
}

// ------- proj GEMM: out = yb[4096][768] @ WpT[768][768]^T + b, 128x128 2-phase ------
#define TILE128_PROLOG() \
  __shared__ __align__(16) ushort lsA[2][128 * 32]; \
  __shared__ __align__(16) ushort lsB[2][128 * 32]; \
  const int tid = threadIdx.x, lane = tid & 63, w = tid >> 6; \
  const int wr = w >> 1, wc = w & 1; \
  const int l15 = lane & 15, l4 = lane >> 4; \
  const int scol = (lane & 3) * 8; \
  const int srow = lane >> 2; \
  f32x4 acc[4][4]; \
  _Pragma("unroll") for (int m = 0; m < 4; ++m) \
    _Pragma("unroll") for (int n = 0; n < 4; ++n) acc[m][n] = (f32x4){0.f, 0.f, 0.f, 0.f};

#define TILE128_LOOP(Aptr, Btptr, lda, ldb, kdim) { \
  const ushort* ga0 = (Aptr) + (size_t)(arow0 + w * 32 + srow) * (lda) + scol; \
  const ushort* ga1 = ga0 + 16 * (lda); \
  const ushort* gb0 = (Btptr) + (size_t)(brow0 + w * 32 + srow) * (ldb) + scol; \
  const ushort* gb1 = gb0 + 16 * (ldb); \
  g2l16(ga0, &lsA[0][(w * 2) * 512]); \
  g2l16(ga1, &lsA[0][(w * 2 + 1) * 512]); \
  g2l16(gb0, &lsB[0][(w * 2) * 512]); \
  g2l16(gb1, &lsB[0][(w * 2 + 1) * 512]); \
  __syncthreads(); \
  int cur = 0; \
  for (int k0 = 0; k0 < (kdim); k0 += 32) { \
    if (k0 + 32 < (kdim)) { \
      g2l16(ga0 + k0 + 32, &lsA[cur ^ 1][(w * 2) * 512]); \
      g2l16(ga1 + k0 + 32, &lsA[cur ^ 1][(w * 2 + 1) * 512]); \
      g2l16(gb0 + k0 + 32, &lsB[cur ^ 1][(w * 2) * 512]); \
      g2l16(gb1 + k0 + 32, &lsB[cur ^ 1][(w * 2 + 1) * 512]); \
    } \
    bf16x8 af[4], bq[4]; \
    _Pragma("unroll") for (int m = 0; m < 4; ++m) \
      af[m] = *(const bf16x8*)(&lsA[cur][(wr * 64 + m * 16 + l15) * 32 + l4 * 8]); \
    _Pragma("unroll") for (int n = 0; n < 4; ++n) \
      bq[n] = *(const bf16x8*)(&lsB[cur][(wc * 64 + n * 16 + l15) * 32 + l4 * 8]); \
    _Pragma("unroll") for (int m = 0; m < 4; ++m) \
      _Pragma("unroll") for (int n = 0; n < 4; ++n) \
        acc[m][n] = __builtin_amdgcn_mfma_f32_16x16x32_bf16(af[m], bq[n], acc[m][n], 0, 0, 0); \
    __syncthreads(); \
    cur ^= 1; \
  } }

__global__ __launch_bounds__(256) void gemm_proj_k(
    const ushort* __restrict__ yb, const ushort* __restrict__ WpT,
    const float* __restrict__ b_proj, float* __restrict__ out) {
  const int arow0 = blockIdx.y * 128, brow0 = blockIdx.x * 128;
  TILE128_PROLOG();
  TILE128_LOOP(yb, WpT, 768, 768, 768);
#pragma unroll
  for (int m = 0; m < 4; ++m)
#pragma unroll
    for (int n = 0; n < 4; ++n) {
      const int gc = brow0 + wc * 64 + n * 16 + l15;
      const float bias = b_proj[gc];
#pragma unroll
      for (int r = 0; r < 4; ++r) {
        const int gr = arow0 + wr * 64 + m * 16 + l4 * 4 + r;
        out[(size_t)gr * 768 + gc] = acc[m][n][r] + bias;
      }
    }
}

// ---------------- S = q k^T per (b,h): heavy q-tiles dispatched first ---------------
__global__ __launch_bounds__(256) void gemm_s_k(
    const ushort* __restrict__ qb, const ushort* __restrict__ kb,
    ushort* __restrict__ SK) {
  const int kt = blockIdx.x, qt = 15 - blockIdx.y, bh = blockIdx.z;
  if (kt > qt) return;
  const int arow0 = qt * 64;
  const int brow0 = kt * 64;
  const ushort* A = qb + ((size_t)bh << 16);
  const ushort* B = kb + ((size_t)bh << 16);
  ushort* S = SK + ((size_t)bh << 20);
  GEMM_PROLOG();
  GEMM_LOOP(A, B, 64, 64, 64);
  GEMM_EPILOG({ S[((size_t)gr << 10) + gc] = f2bf(val); });
}

// ---- FUSED: row softmax -> D = 1-exp(-p) in place (band write) -> Sinkhorn iter 1 --
__global__ __launch_bounds__(256) void kmat_k(ushort* __restrict__ SK,
                                              float* __restrict__ u,
                                              float* __restrict__ colpart) {
  const int pair = blockIdx.x, bh = blockIdx.y;
  const int tid = threadIdx.x, lane = tid & 63, w = tid >> 6;
  ushort* base = SK + ((size_t)bh << 20);
  const int cA = lane, cB = lane + 64;
  __shared__ float cred[4][1024];
  uint4 z4 = make_uint4(0, 0, 0, 0);
  for (int half = 0; half < 2; ++half) {
    const int stripe = half ? pair : (63 - pair);
    const int rstart = stripe * 16 + w * 4;
    float ca[16];
#pragma unroll
    for (int e = 0; e < 16; ++e) ca[e] = 0.f;
    for (int r = 0; r < 4; ++r) {
      const int i = rstart + r;
      ushort* row = base + ((size_t)i << 10);
      const int nc8 = i >> 3;
      uint4 da = (cA <= nc8) ? *(const uint4*)(row + 8 * cA) : z4;
      uint4 db = (cB <= nc8) ? *(const uint4*)(row + 8 * cB) : z4;
      float xa[8], xb[8];
      up8(da, xa); up8(db, xb);
      float m = -1e30f;
#pragma unroll
      for (int e = 0; e < 8; ++e) {
        if (8 * cA + e <= i) m = fmaxf(m, xa[e]);
        if (8 * cB + e <= i) m = fmaxf(m, xb[e]);
      }
#pragma unroll
      for (int o = 1; o < 64; o <<= 1) m = fmaxf(m, __shfl_xor(m, o));
      float pa[8], pb[8];
      float s = 0.f;
#pragma unroll
      for (int e = 0; e < 8; ++e) {
        pa[e] = (8 * cA + e <= i) ? __expf(xa[e] - m) : 0.f;
        pb[e] = (8 * cB + e <= i) ? __expf(xb[e] - m) : 0.f;
        s += pa[e] + pb[e];
      }
#pragma unroll
      for (int o = 1; o < 64; o <<= 1) s += __shfl_xor(s, o);
      const float inv = 1.0f / s;
      float Da[8], Db[8];
      float rs = 0.f;
#pragma unroll
      for (int e = 0; e < 8; ++e) {
        Da[e] = (8 * cA + e <= i) ? (1.0f - __expf(-pa[e] * inv)) : 0.f;
        Db[e] = (8 * cB + e <= i) ? (1.0f - __expf(-pb[e] * inv)) : 0.f;
        rs += Da[e] + Db[e];
      }
#pragma unroll
      for (int o = 1; o < 64; o <<= 1) rs += __shfl_xor(rs, o);
      const float ui = MU / (1024.0f - rs);
      if (lane == 0) u[(bh << 10) + i] = ui;
      const int bandc = ((i >> 6) + 1) << 3;
      if (cA < bandc) *(uint4*)(row + 8 * cA) = pk8(Da);
      if (cB < bandc) *(uint4*)(row + 8 * cB) = pk8(Db);
#pragma unroll
      for (int e = 0; e < 8; ++e) { ca[e] += ui * Da[e]; ca[8 + e] += ui * Db[e]; }
    }
    if (half) __syncthreads();
#pragma unroll
    for (int e = 0; e < 16; ++e) cred[w][e * 64 + lane] = ca[e];
    __syncthreads();
    float* cp = colpart + (((size_t)stripe * 48 + bh) << 10);
#pragma unroll
    for (int pp = 0; pp < 4; ++pp) {
      int p = tid + pp * 256;
      cp[p] = cred[0][p] + cred[1][p] + cred[2][p] + cred[3][p];
    }
  }
}

// ------ fused Sinkhorn half-sweep (iters 2..6): u_i = MU/(sv - D_i·v); colacc -------
// grid (32 stripe-pairs, 48 bh); 16-row stripes; packed f32 FMA inner loop.
__global__ __launch_bounds__(256) void sink_k(
    const ushort* __restrict__ SK, const float* __restrict__ vv,
    float* __restrict__ u, float* __restrict__ colpart) {
  const int pair = blockIdx.x, bh = blockIdx.y;
  const int tid = threadIdx.x, lane = tid & 63, w = tid >> 6;
  const ushort* base = SK + ((size_t)bh << 20);
  const f32x2* vb2 = (const f32x2*)(vv + (bh << 10));
  f32x2 vr2[8];
#pragma unroll
  for (int e2 = 0; e2 < 4; ++e2) {
    vr2[e2]     = vb2[4 * lane + e2];
    vr2[4 + e2] = vb2[256 + 4 * lane + e2];
  }
  float sv = 0.f;
#pragma unroll
  for (int e2 = 0; e2 < 8; ++e2) sv += vr2[e2].x + vr2[e2].y;
#pragma unroll
  for (int o = 1; o < 64; o <<= 1) sv += __shfl_xor(sv, o);
  __shared__ float cred[4][1024];
  uint4 z4 = make_uint4(0, 0, 0, 0);
  for (int half = 0; half < 2; ++half) {
    const int stripe = half ? pair : (63 - pair);
    const int rstart = stripe * 16 + w * 4;
    f32x2 ca2[8];
#pragma unroll
    for (int e2 = 0; e2 < 8; ++e2) ca2[e2] = (f32x2){0.f, 0.f};
    for (int r = 0; r < 4; ++r) {
      const int i = rstart + r;
      const ushort* row = base + ((size_t)i << 10);
      const int nc8 = i >> 3;
      uint4 da = (lane <= nc8)      ? *(const uint4*)(row + 8 * lane)       : z4;
      uint4 db = (lane + 64 <= nc8) ? *(const uint4*)(row + 512 + 8 * lane) : z4;
      f32x2 d2[8];
      up8p(da, d2); up8p(db, d2 + 4);
      f32x2 acc2 = (f32x2){0.f, 0.f};
#pragma unroll
      for (int e2 = 0; e2 < 8; ++e2) acc2 = pkfma(d2[e2], vr2[e2], acc2);
      float a = acc2.x + acc2.y;
#pragma unroll
      for (int o = 1; o < 64; o <<= 1) a += __shfl_xor(a, o);
      const float ui = MU / (sv - a);
      if (lane == 0) u[(bh << 10) + i] = ui;
      const f32x2 uu = (f32x2){ui, ui};
#pragma unroll
      for (int e2 = 0; e2 < 8; ++e2) ca2[e2] = pkfma(uu, d2[e2], ca2[e2]);
    }
    if (half) __syncthreads();
    const float* caf = (const float*)ca2;
#pragma unroll
    for (int e = 0; e < 16; ++e) cred[w][e * 64 + lane] = caf[e];
    __syncthreads();
    float* cp = colpart + (((size_t)stripe * 48 + bh) << 10);
#pragma unroll
    for (int pp = 0; pp < 4; ++pp) {
      int p = tid + pp * 256;
      cp[p] = cred[0][p] + cred[1][p] + cred[2][p] + cred[3][p];
    }
  }
}

// ------ finish v-update: v_j = MU/(su - colsum_j). grid (4 col-chunks, 48 bh) -------
__global__ __launch_bounds__(256) void vfin_k(
    const float* __restrict__ colpart, const float* __restrict__ u,
    float* __restrict__ vv) {
  const int cq = blockIdx.x, bh = blockIdx.y;
  const int tid = threadIdx.x;
  float su = 0.f;
  for (int t = tid; t < 1024; t += 256) su += u[(bh << 10) + t];
#pragma unroll
  for (int o = 1; o < 64; o <<= 1) su += __shfl_xor(su, o);
  __shared__ float red[4];
  if ((tid & 63) == 0) red[tid >> 6] = su;
  __syncthreads();
  su = red[0] + red[1] + red[2] + red[3];
  const int c = cq * 256 + tid;
  const int p = permcol(c);
  float s = 0.f;
  for (int st = 0; st < 64; ++st)
    s += colpart[(((size_t)st * 48 + bh) << 10) + p];
  vv[(bh << 10) + c] = MU / (su - s);
}

// ---------------- V' = v ⊙ V (bf16, d-major) + Wd[bh][d] = sum_t V'[t][d] -----------
__global__ __launch_bounds__(256) void vprep_k(const float* __restrict__ Vt,
                                               const float* __restrict__ vv,
                                               ushort* __restrict__ Vpt,
                                               float* __restrict__ Wd) {
  const int bd = blockIdx.x;
  const int bh = bd >> 6;
  const int tid = threadIdx.x;
  const float* src = Vt + ((size_t)bd << 10);
  const float* vb = vv + (bh << 10);
  ushort* dst = Vpt + ((size_t)bd << 10);
  float s = 0.f;
  for (int t = tid; t < 1024; t += 256) {
    float p = src[t] * vb[t];
    s += p;
    dst[t] = f2bf(p);
  }
  for (int o = 32; o; o >>= 1) s += __shfl_down(s, o);
  __shared__ float red[4];
  if ((tid & 63) == 0) red[tid >> 6] = s;
  __syncthreads();
  if (tid == 0) Wd[bd] = red[0] + red[1] + red[2] + red[3];
}

// ------- y = 1024*u ⊙ (Wd - D @ V'), heavy q-tiles first (triangular K) -------------
__global__ __launch_bounds__(256) void gemm_pv_k(
    const ushort* __restrict__ SK, const ushort* __restrict__ Vpt,
    const float* __restrict__ u, const float* __restrict__ Wd,
    ushort* __restrict__ yb) {
  const int qt = 15 - blockIdx.y, bh = blockIdx.z;
  const int arow0 = qt * 64;
  const int brow0 = 0;
  const int kdim = (qt + 1) << 6;
  const ushort* A = SK + ((size_t)bh << 20);
  const ushort* B = Vpt + ((size_t)bh << 16);
  GEMM_PROLOG();
  GEMM_LOOP(A, B, 1024, 1024, kdim);
  const int bb = bh / 12, h = bh - bb * 12;
  GEMM_EPILOG({
    float yv = (Wd[(bh << 6) + gc] - val) * u[(bh << 10) + gr] * 1024.0f;
    yb[((size_t)((bb << 10) + gr)) * 768 + (h << 6) + gc] = f2bf(yv);
  });
}

// ------------------------------------------------------------------------------------
extern "C" void kernel_launch(void* const* d_in, const int* in_sizes, int n_in,
                              void* d_out, int out_size, void* d_ws, size_t ws_size,
                              hipStream_t stream) {
  const float* x      = (const float*)d_in[0];
  const float* ln_w   = (const float*)d_in[1];
  const float* ln_b   = (const float*)d_in[2];
  const float* W_attn = (const float*)d_in[3];
  const float* b_attn = (const float*)d_in[4];
  const float* W_proj = (const float*)d_in[5];
  const float* b_proj = (const float*)d_in[6];
  float* out = (float*)d_out;
  char* ws = (char*)d_ws;

  // ws layout (bytes); peak use ~144 MB
  ushort* xnb = (ushort*)(ws + 0);            // 4096*832 bf16 (dead after gemm_qkv)
  ushort* WaT = (ushort*)(ws + 6815744);      // 2304*832 bf16
  ushort* WpT = (ushort*)(ws + 10649600);     // 768*768 bf16
  ushort* qb  = (ushort*)(ws + 11829248);     // 48*1024*64 bf16 (dead after gemm_s)
  ushort* kb  = (ushort*)(ws + 18120704);     // 48*1024*64 bf16 (dead after gemm_s)
  float*  Vt  = (float*) (ws + 24412160);     // 48*64*1024 f32 (dead after vprep)
  ushort* SK  = (ushort*)(ws + 36995072);     // 48*1024*1024 bf16 (S, then D)
  ushort* Vpt = (ushort*)(ws + 137658368);    // 48*64*1024 bf16
  // overlays:
  float*  colpart = (float*)(ws + 11829248);  // 64*48*1024 f32 on dead qb/kb
  ushort* yb  = (ushort*)(ws + 24412160);     // 4096*768 bf16 on dead Vt
  float*  u   = (float*) (ws + 0);            // 48*1024 f32 on dead xnb
  float*  vv  = (float*) (ws + 196608);       //   "
  float*  Wd  = (float*) (ws + 393216);       //   "

  hipLaunchKernelGGL(ln_k, dim3(4096), dim3(256), 0, stream, x, ln_w, ln_b, xnb);
  hipLaunchKernelGGL(tr_k, dim3(72, 26), dim3(256), 0, stream, W_attn, WaT, 769, 2304, 832);
  hipLaunchKernelGGL(tr_k, dim3(24, 24), dim3(256), 0, stream, W_proj, WpT, 768, 768, 768);
  hipLaunchKernelGGL(gemm_qkv_k, dim3(18, 32), dim3(256), 0, stream,
                     xnb, WaT, b_attn, qb, kb, Vt);
  hipLaunchKernelGGL(gemm_s_k, dim3(16, 16, 48), dim3(256), 0, stream, qb, kb, SK);
  hipLaunchKernelGGL(kmat_k, dim3(32, 48), dim3(256), 0, stream, SK, u, colpart);
  hipLaunchKernelGGL(vfin_k, dim3(4, 48), dim3(256), 0, stream, colpart, u, vv);
  for (int it = 0; it < 5; ++it) {
    hipLaunchKernelGGL(sink_k, dim3(32, 48), dim3(256), 0, stream, SK, vv, u, colpart);
    hipLaunchKernelGGL(vfin_k, dim3(4, 48), dim3(256), 0, stream, colpart, u, vv);
  }
  hipLaunchKernelGGL(vprep_k, dim3(3072), dim3(256), 0, stream, Vt, vv, Vpt, Wd);
  hipLaunchKernelGGL(gemm_pv_k, dim3(1, 16, 48), dim3(256), 0, stream, SK, Vpt, u, Wd, yb);
  hipLaunchKernelGGL(gemm_proj_k, dim3(6, 32), dim3(256), 0, stream, yb, WpT, b_proj, out);
}

// Round 10
// 296.637 us; speedup vs baseline: 3.5228x; 1.0487x over previous
//
#include <hip/hip_runtime.h>

typedef float f32x4 __attribute__((ext_vector_type(4)));
typedef float f32x2 __attribute__((ext_vector_type(2)));
typedef __bf16 bf16x8 __attribute__((ext_vector_type(8)));

#define MU (1.0f / 1024.0f)

__device__ __forceinline__ float bf2f(ushort u) {
  union { uint i; float f; } v; v.i = ((uint)u) << 16; return v.f;
}
__device__ __forceinline__ ushort f2bf(float f) {
  union { float f; uint i; } v; v.f = f;
  uint r = v.i + 0x7fffu + ((v.i >> 16) & 1u);  // RNE
  return (ushort)(r >> 16);
}
__device__ __forceinline__ void up8(uint4 v, float* o) {
  o[0] = bf2f((ushort)v.x); o[1] = bf2f((ushort)(v.x >> 16));
  o[2] = bf2f((ushort)v.y); o[3] = bf2f((ushort)(v.y >> 16));
  o[4] = bf2f((ushort)v.z); o[5] = bf2f((ushort)(v.z >> 16));
  o[6] = bf2f((ushort)v.w); o[7] = bf2f((ushort)(v.w >> 16));
}
__device__ __forceinline__ uint4 pk8(const float* f) {
  uint4 r;
  r.x = (uint)f2bf(f[0]) | ((uint)f2bf(f[1]) << 16);
  r.y = (uint)f2bf(f[2]) | ((uint)f2bf(f[3]) << 16);
  r.z = (uint)f2bf(f[4]) | ((uint)f2bf(f[5]) << 16);
  r.w = (uint)f2bf(f[6]) | ((uint)f2bf(f[7]) << 16);
  return r;
}
// unpack 8 bf16 -> 4 packed f32x2
__device__ __forceinline__ void up8p(uint4 v, f32x2* o) {
  union { uint i; float f; } a, b;
  a.i = v.x << 16; b.i = v.x & 0xffff0000u; o[0] = (f32x2){a.f, b.f};
  a.i = v.y << 16; b.i = v.y & 0xffff0000u; o[1] = (f32x2){a.f, b.f};
  a.i = v.z << 16; b.i = v.z & 0xffff0000u; o[2] = (f32x2){a.f, b.f};
  a.i = v.w << 16; b.i = v.w & 0xffff0000u; o[3] = (f32x2){a.f, b.f};
}
__device__ __forceinline__ f32x2 pkfma(f32x2 a, f32x2 b, f32x2 c) {
  f32x2 d;
  asm("v_pk_fma_f32 %0, %1, %2, %3" : "=v"(d) : "v"(a), "v"(b), "v"(c));
  return d;
}
__device__ __forceinline__ int permcol(int c) {
  return (c < 512) ? ((c & 7) * 64 + (c >> 3))
                   : ((8 + ((c - 512) & 7)) * 64 + ((c - 512) >> 3));
}

// async global->LDS, 16B per lane; lds base must be wave-uniform
typedef const __attribute__((address_space(1))) void gvoid;
typedef __attribute__((address_space(3))) void lvoid;
__device__ __forceinline__ void g2l16(const void* g, void* l) {
  __builtin_amdgcn_global_load_lds((gvoid*)g, (lvoid*)l, 16, 0, 0);
}

// ---------------- LayerNorm: x[4096][769] f32 -> xnb[4096][832] bf16 (zero-pad K) ---
__global__ __launch_bounds__(256) void ln_k(const float* __restrict__ x,
                                            const float* __restrict__ w,
                                            const float* __restrict__ b,
                                            ushort* __restrict__ xnb) {
  const int row = blockIdx.x;
  const int tid = threadIdx.x;
  const float* xr = x + (size_t)row * 769;
  float s = 0.f, ss = 0.f;
  for (int c = tid; c < 769; c += 256) { float v = xr[c]; s += v; ss += v * v; }
  for (int o = 32; o; o >>= 1) { s += __shfl_down(s, o); ss += __shfl_down(ss, o); }
  __shared__ float rs[4], rss[4];
  if ((tid & 63) == 0) { rs[tid >> 6] = s; rss[tid >> 6] = ss; }
  __syncthreads();
  s  = rs[0] + rs[1] + rs[2] + rs[3];
  ss = rss[0] + rss[1] + rss[2] + rss[3];
  const float mean = s * (1.0f / 769.0f);
  const float var  = ss * (1.0f / 769.0f) - mean * mean;
  const float rstd = rsqrtf(var + 1e-5f);
  ushort* orow = xnb + (size_t)row * 832;
  for (int c = tid; c < 832; c += 256) {
    float o = 0.f;
    if (c < 769) o = (xr[c] - mean) * rstd * w[c] + b[c];
    orow[c] = f2bf(o);
  }
}

// ---------------- transpose W[K][N] f32 -> Wt[N][Kp] bf16 (zero-pad K..Kp) ----------
__global__ __launch_bounds__(256) void tr_k(const float* __restrict__ W,
                                            ushort* __restrict__ Wt,
                                            int K, int N, int Kp) {
  __shared__ float ls[32][33];
  const int n0 = blockIdx.x * 32, k0 = blockIdx.y * 32;
  const int c = threadIdx.x & 31, r = threadIdx.x >> 5;  // r in 0..7
  for (int rr = 0; rr < 32; rr += 8) {
    int k = k0 + r + rr;
    ls[r + rr][c] = (k < K) ? W[(size_t)k * N + n0 + c] : 0.f;
  }
  __syncthreads();
  for (int rr = 0; rr < 32; rr += 8) {
    int n = n0 + r + rr;
    if (k0 + c < Kp) Wt[(size_t)n * Kp + k0 + c] = f2bf(ls[c][r + rr]);
  }
}

// ---------------- shared 64x64 GEMM core (used by gemm_s / gemm_pv) -----------------
#define GEMM_PROLOG() \
  __shared__ __align__(16) ushort lsA[64 * 40]; \
  __shared__ __align__(16) ushort lsB[64 * 40]; \
  const int tid = threadIdx.x; \
  const int lane = tid & 63; \
  const int wid = tid >> 6; \
  const int wr = wid >> 1, wc = wid & 1; \
  const int l15 = lane & 15, l4 = lane >> 4; \
  const int srow = tid >> 2, scol = (tid & 3) << 3; \
  f32x4 acc00 = {0.f, 0.f, 0.f, 0.f}; \
  f32x4 acc01 = acc00, acc10 = acc00, acc11 = acc00;

#define GEMM_LOOP(Aptr, Btptr, lda, ldb, kdim) \
  { const size_t aoff0 = (size_t)(arow0 + srow) * (lda) + scol; \
    const size_t boff0 = (size_t)(brow0 + srow) * (ldb) + scol; \
    for (int k0 = 0; k0 < (kdim); k0 += 32) { \
      uint4 av = *(const uint4*)((Aptr) + aoff0 + k0); \
      uint4 bv = *(const uint4*)((Btptr) + boff0 + k0); \
      __syncthreads(); \
      *(uint4*)(lsA + srow * 40 + scol) = av; \
      *(uint4*)(lsB + srow * 40 + scol) = bv; \
      __syncthreads(); \
      bf16x8 af0 = *(const bf16x8*)(lsA + (wr * 32 + l15) * 40 + l4 * 8); \
      bf16x8 af1 = *(const bf16x8*)(lsA + (wr * 32 + 16 + l15) * 40 + l4 * 8); \
      bf16x8 bq0 = *(const bf16x8*)(lsB + (wc * 32 + l15) * 40 + l4 * 8); \
      bf16x8 bq1 = *(const bf16x8*)(lsB + (wc * 32 + 16 + l15) * 40 + l4 * 8); \
      acc00 = __builtin_amdgcn_mfma_f32_16x16x32_bf16(af0, bq0, acc00, 0, 0, 0); \
      acc01 = __builtin_amdgcn_mfma_f32_16x16x32_bf16(af0, bq1, acc01, 0, 0, 0); \
      acc10 = __builtin_amdgcn_mfma_f32_16x16x32_bf16(af1, bq0, acc10, 0, 0, 0); \
      acc11 = __builtin_amdgcn_mfma_f32_16x16x32_bf16(af1, bq1, acc11, 0, 0, 0); \
    } }

#define EPI_ONE(ACC, FM, FN, ...) \
  { _Pragma("unroll") for (int r = 0; r < 4; ++r) { \
      int gr = arow0 + wr * 32 + (FM) * 16 + l4 * 4 + r; \
      int gc = brow0 + wc * 32 + (FN) * 16 + l15; \
      float val = ACC[r]; \
      __VA_ARGS__; \
  } }
#define GEMM_EPILOG(...) \
  EPI_ONE(acc00, 0, 0, __VA_ARGS__) EPI_ONE(acc01, 0, 1, __VA_ARGS__) \
  EPI_ONE(acc10, 1, 0, __VA_ARGS__) EPI_ONE(acc11, 1, 1, __VA_ARGS__)

// ------- QKV GEMM, 128x128 tile, BK=64, 2-phase dbuf, XOR-swizzled LDS --------------
__global__ __launch_bounds__(256) void gemm_qkv_k(
    const ushort* __restrict__ xnb, const ushort* __restrict__ WaT,
    const float* __restrict__ b_attn,
    ushort* __restrict__ qb, ushort* __restrict__ kb, float* __restrict__ Vt) {
  __shared__ __align__(16) ushort lsA[2][128 * 64];
  __shared__ __align__(16) ushort lsB[2][128 * 64];
  const int tid = threadIdx.x, lane = tid & 63, w = tid >> 6;
  const int wr = w >> 1, wc = w & 1;
  const int l15 = lane & 15, l4 = lane >> 4;
  const int arow0 = blockIdx.y * 128, brow0 = blockIdx.x * 128;
  f32x4 acc[4][4];
#pragma unroll
  for (int m = 0; m < 4; ++m)
#pragma unroll
    for (int n = 0; n < 4; ++n) acc[m][n] = (f32x4){0.f, 0.f, 0.f, 0.f};

  const int srow = (lane >> 3);
  const int scol16 = ((lane & 7) ^ srow) * 8;   // pre-swizzled source chunk
  const ushort* gA = xnb + (size_t)(arow0 + w * 32 + srow) * 832 + scol16;
  const ushort* gB = WaT + (size_t)(brow0 + w * 32 + srow) * 832 + scol16;

#define QKV_STAGE(buf, k0) { \
  _Pragma("unroll") for (int s = 0; s < 4; ++s) { \
    g2l16(gA + (size_t)(s * 8) * 832 + (k0), &lsA[buf][(w * 32 + s * 8) * 64]); \
    g2l16(gB + (size_t)(s * 8) * 832 + (k0), &lsB[buf][(w * 32 + s * 8) * 64]); \
  } }

  QKV_STAGE(0, 0);
  __syncthreads();
  int cur = 0;
  for (int k0 = 0; k0 < 832; k0 += 64) {
    if (k0 + 64 < 832) QKV_STAGE(cur ^ 1, k0 + 64);
    bf16x8 af[2][4], bq[2][4];
#pragma unroll
    for (int kk = 0; kk < 2; ++kk) {
#pragma unroll
      for (int m = 0; m < 4; ++m) {
        const int r = wr * 64 + m * 16 + l15;
        af[kk][m] = *(const bf16x8*)(&lsA[cur][r * 64 + (((kk * 4 + l4) ^ (l15 & 7)) * 8)]);
      }
#pragma unroll
      for (int n = 0; n < 4; ++n) {
        const int r = wc * 64 + n * 16 + l15;
        bq[kk][n] = *(const bf16x8*)(&lsB[cur][r * 64 + (((kk * 4 + l4) ^ (l15 & 7)) * 8)]);
      }
    }
#pragma unroll
    for (int kk = 0; kk < 2; ++kk)
#pragma unroll
      for (int m = 0; m < 4; ++m)
#pragma unroll
        for (int n = 0; n < 4; ++n)
          acc[m][n] = __builtin_amdgcn_mfma_f32_16x16x32_bf16(af[kk][m], bq[kk][n], acc[m][n], 0, 0, 0);
    __syncthreads();
    cur ^= 1;
  }

#pragma unroll
  for (int m = 0; m < 4; ++m)
#pragma unroll
    for (int n = 0; n < 4; ++n) {
      const int gc = brow0 + wc * 64 + n * 16 + l15;
      const float bias = b_attn[gc];
      const int sect = gc / 768;
      const int e = gc - sect * 768;
      const int h = e >> 6;
      const int d = e & 63;
#pragma unroll
      for (int r = 0; r < 4; ++r) {
        const int gr = arow0 + wr * 64 + m * 16 + l4 * 4 + r;
        const int bb = gr >> 10;
        const int t = gr & 1023;
        const size_t bh = (size_t)(bb * 12 + h);
        const float val = acc[m][n][r] + bias;
        if (sect == 0)      qb[(bh << 16) + ((size_t)t << 6) + d] = f2bf(val * 0.125f);
        else if (sect == 1) kb[(bh << 16) + ((size_t)t << 6) + d] = f2bf(val);
        else                Vt[(bh << 16) + ((size_t)d << 10) + t] = val;
      }
    }
}

// ------- proj GEMM: out = yb[4096][768] @ WpT[768][768]^T + b, 128x128 2-phase ------
#define TILE128_PROLOG() \
  __shared__ __align__(16) ushort lsA[2][128 * 32]; \
  __shared__ __align__(16) ushort lsB[2][128 * 32]; \
  const int tid = threadIdx.x, lane = tid & 63, w = tid >> 6; \
  const int wr = w >> 1, wc = w & 1; \
  const int l15 = lane & 15, l4 = lane >> 4; \
  const int scol = (lane & 3) * 8; \
  const int srow = lane >> 2; \
  f32x4 acc[4][4]; \
  _Pragma("unroll") for (int m = 0; m < 4; ++m) \
    _Pragma("unroll") for (int n = 0; n < 4; ++n) acc[m][n] = (f32x4){0.f, 0.f, 0.f, 0.f};

#define TILE128_LOOP(Aptr, Btptr, lda, ldb, kdim) { \
  const ushort* ga0 = (Aptr) + (size_t)(arow0 + w * 32 + srow) * (lda) + scol; \
  const ushort* ga1 = ga0 + 16 * (lda); \
  const ushort* gb0 = (Btptr) + (size_t)(brow0 + w * 32 + srow) * (ldb) + scol; \
  const ushort* gb1 = gb0 + 16 * (ldb); \
  g2l16(ga0, &lsA[0][(w * 2) * 512]); \
  g2l16(ga1, &lsA[0][(w * 2 + 1) * 512]); \
  g2l16(gb0, &lsB[0][(w * 2) * 512]); \
  g2l16(gb1, &lsB[0][(w * 2 + 1) * 512]); \
  __syncthreads(); \
  int cur = 0; \
  for (int k0 = 0; k0 < (kdim); k0 += 32) { \
    if (k0 + 32 < (kdim)) { \
      g2l16(ga0 + k0 + 32, &lsA[cur ^ 1][(w * 2) * 512]); \
      g2l16(ga1 + k0 + 32, &lsA[cur ^ 1][(w * 2 + 1) * 512]); \
      g2l16(gb0 + k0 + 32, &lsB[cur ^ 1][(w * 2) * 512]); \
      g2l16(gb1 + k0 + 32, &lsB[cur ^ 1][(w * 2 + 1) * 512]); \
    } \
    bf16x8 af[4], bq[4]; \
    _Pragma("unroll") for (int m = 0; m < 4; ++m) \
      af[m] = *(const bf16x8*)(&lsA[cur][(wr * 64 + m * 16 + l15) * 32 + l4 * 8]); \
    _Pragma("unroll") for (int n = 0; n < 4; ++n) \
      bq[n] = *(const bf16x8*)(&lsB[cur][(wc * 64 + n * 16 + l15) * 32 + l4 * 8]); \
    _Pragma("unroll") for (int m = 0; m < 4; ++m) \
      _Pragma("unroll") for (int n = 0; n < 4; ++n) \
        acc[m][n] = __builtin_amdgcn_mfma_f32_16x16x32_bf16(af[m], bq[n], acc[m][n], 0, 0, 0); \
    __syncthreads(); \
    cur ^= 1; \
  } }

__global__ __launch_bounds__(256) void gemm_proj_k(
    const ushort* __restrict__ yb, const ushort* __restrict__ WpT,
    const float* __restrict__ b_proj, float* __restrict__ out) {
  const int arow0 = blockIdx.y * 128, brow0 = blockIdx.x * 128;
  TILE128_PROLOG();
  TILE128_LOOP(yb, WpT, 768, 768, 768);
#pragma unroll
  for (int m = 0; m < 4; ++m)
#pragma unroll
    for (int n = 0; n < 4; ++n) {
      const int gc = brow0 + wc * 64 + n * 16 + l15;
      const float bias = b_proj[gc];
#pragma unroll
      for (int r = 0; r < 4; ++r) {
        const int gr = arow0 + wr * 64 + m * 16 + l4 * 4 + r;
        out[(size_t)gr * 768 + gc] = acc[m][n][r] + bias;
      }
    }
}

// ---------------- S = q k^T per (b,h): heavy q-tiles dispatched first ---------------
__global__ __launch_bounds__(256) void gemm_s_k(
    const ushort* __restrict__ qb, const ushort* __restrict__ kb,
    ushort* __restrict__ SK) {
  const int kt = blockIdx.x, qt = 15 - blockIdx.y, bh = blockIdx.z;
  if (kt > qt) return;
  const int arow0 = qt * 64;
  const int brow0 = kt * 64;
  const ushort* A = qb + ((size_t)bh << 16);
  const ushort* B = kb + ((size_t)bh << 16);
  ushort* S = SK + ((size_t)bh << 20);
  GEMM_PROLOG();
  GEMM_LOOP(A, B, 64, 64, 64);
  GEMM_EPILOG({ S[((size_t)gr << 10) + gc] = f2bf(val); });
}

// ---- FUSED: row softmax -> D = 1-exp(-p) in place (band write) -> Sinkhorn iter 1 --
// writes colpart with depth 64 (stripe-major)
__global__ __launch_bounds__(256) void kmat_k(ushort* __restrict__ SK,
                                              float* __restrict__ u,
                                              float* __restrict__ colpart) {
  const int pair = blockIdx.x, bh = blockIdx.y;
  const int tid = threadIdx.x, lane = tid & 63, w = tid >> 6;
  ushort* base = SK + ((size_t)bh << 20);
  const int cA = lane, cB = lane + 64;
  __shared__ float cred[4][1024];
  uint4 z4 = make_uint4(0, 0, 0, 0);
  for (int half = 0; half < 2; ++half) {
    const int stripe = half ? pair : (63 - pair);
    const int rstart = stripe * 16 + w * 4;
    float ca[16];
#pragma unroll
    for (int e = 0; e < 16; ++e) ca[e] = 0.f;
    for (int r = 0; r < 4; ++r) {
      const int i = rstart + r;
      ushort* row = base + ((size_t)i << 10);
      const int nc8 = i >> 3;
      uint4 da = (cA <= nc8) ? *(const uint4*)(row + 8 * cA) : z4;
      uint4 db = (cB <= nc8) ? *(const uint4*)(row + 8 * cB) : z4;
      float xa[8], xb[8];
      up8(da, xa); up8(db, xb);
      float m = -1e30f;
#pragma unroll
      for (int e = 0; e < 8; ++e) {
        if (8 * cA + e <= i) m = fmaxf(m, xa[e]);
        if (8 * cB + e <= i) m = fmaxf(m, xb[e]);
      }
#pragma unroll
      for (int o = 1; o < 64; o <<= 1) m = fmaxf(m, __shfl_xor(m, o));
      float pa[8], pb[8];
      float s = 0.f;
#pragma unroll
      for (int e = 0; e < 8; ++e) {
        pa[e] = (8 * cA + e <= i) ? __expf(xa[e] - m) : 0.f;
        pb[e] = (8 * cB + e <= i) ? __expf(xb[e] - m) : 0.f;
        s += pa[e] + pb[e];
      }
#pragma unroll
      for (int o = 1; o < 64; o <<= 1) s += __shfl_xor(s, o);
      const float inv = 1.0f / s;
      float Da[8], Db[8];
      float rs = 0.f;
#pragma unroll
      for (int e = 0; e < 8; ++e) {
        Da[e] = (8 * cA + e <= i) ? (1.0f - __expf(-pa[e] * inv)) : 0.f;
        Db[e] = (8 * cB + e <= i) ? (1.0f - __expf(-pb[e] * inv)) : 0.f;
        rs += Da[e] + Db[e];
      }
#pragma unroll
      for (int o = 1; o < 64; o <<= 1) rs += __shfl_xor(rs, o);
      const float ui = MU / (1024.0f - rs);
      if (lane == 0) u[(bh << 10) + i] = ui;
      const int bandc = ((i >> 6) + 1) << 3;
      if (cA < bandc) *(uint4*)(row + 8 * cA) = pk8(Da);
      if (cB < bandc) *(uint4*)(row + 8 * cB) = pk8(Db);
#pragma unroll
      for (int e = 0; e < 8; ++e) { ca[e] += ui * Da[e]; ca[8 + e] += ui * Db[e]; }
    }
    if (half) __syncthreads();
#pragma unroll
    for (int e = 0; e < 16; ++e) cred[w][e * 64 + lane] = ca[e];
    __syncthreads();
    float* cp = colpart + (((size_t)stripe * 48 + bh) << 10);
#pragma unroll
    for (int pp = 0; pp < 4; ++pp) {
      int p = tid + pp * 256;
      cp[p] = cred[0][p] + cred[1][p] + cred[2][p] + cred[3][p];
    }
  }
}

// ------ fused Sinkhorn half-sweep (iters 2..6), complementary row-pairing -----------
// grid (16, 48); wave g=blk*4+w handles 8 pairs (i, 1023-i), i = 512+g*8+r.
// Lane loads: chunk L of row i (always valid), chunk L+64 of row i and chunk L of
// row j with complementary masks -> ~2 valid loads/lane uniformly.
// colpart depth 16 (one entry per block).
__global__ __launch_bounds__(256) void sink_k(
    const ushort* __restrict__ SK, const float* __restrict__ vv,
    float* __restrict__ u, float* __restrict__ colpart) {
  const int blk = blockIdx.x, bh = blockIdx.y;
  const int tid = threadIdx.x, lane = tid & 63, w = tid >> 6;
  const int g = blk * 4 + w;                       // 0..63
  const ushort* base = SK + ((size_t)bh << 20);
  const f32x2* vb2 = (const f32x2*)(vv + (bh << 10));
  f32x2 vr2[8];
#pragma unroll
  for (int e2 = 0; e2 < 4; ++e2) {
    vr2[e2]     = vb2[4 * lane + e2];              // cols 8*lane .. +7
    vr2[4 + e2] = vb2[256 + 4 * lane + e2];        // cols 512+8*lane .. +7
  }
  float sv = 0.f;
#pragma unroll
  for (int e2 = 0; e2 < 8; ++e2) sv += vr2[e2].x + vr2[e2].y;
#pragma unroll
  for (int o = 1; o < 64; o <<= 1) sv += __shfl_xor(sv, o);

  f32x2 caA[4], caB[4];
#pragma unroll
  for (int e2 = 0; e2 < 4; ++e2) { caA[e2] = (f32x2){0.f, 0.f}; caB[e2] = (f32x2){0.f, 0.f}; }
  uint4 z4 = make_uint4(0, 0, 0, 0);
  float* ub = u + (bh << 10);

  for (int r = 0; r < 8; ++r) {
    const int i = 512 + g * 8 + r;
    const int j = 1023 - i;
    const ushort* rowi = base + ((size_t)i << 10);
    const ushort* rowj = base + ((size_t)j << 10);
    uint4 da = *(const uint4*)(rowi + 8 * lane);   // always valid (i >= 512)
    uint4 db = (lane + 64 <= (i >> 3)) ? *(const uint4*)(rowi + 512 + 8 * lane) : z4;
    uint4 dc = (lane <= (j >> 3))      ? *(const uint4*)(rowj + 8 * lane)       : z4;
    f32x2 d2a[4], d2b[4], d2c[4];
    up8p(da, d2a); up8p(db, d2b); up8p(dc, d2c);
    f32x2 di2 = (f32x2){0.f, 0.f}, dj2 = (f32x2){0.f, 0.f};
#pragma unroll
    for (int e2 = 0; e2 < 4; ++e2) {
      di2 = pkfma(d2a[e2], vr2[e2], di2);
      di2 = pkfma(d2b[e2], vr2[4 + e2], di2);
      dj2 = pkfma(d2c[e2], vr2[e2], dj2);
    }
    union { double d; float f[2]; } pk;
    pk.f[0] = di2.x + di2.y;
    pk.f[1] = dj2.x + dj2.y;
#pragma unroll
    for (int o = 1; o < 64; o <<= 1) {
      union { double d; float f[2]; } q;
      q.d = __shfl_xor(pk.d, o);
      pk.f[0] += q.f[0];
      pk.f[1] += q.f[1];
    }
    const float ui = MU / (sv - pk.f[0]);
    const float uj = MU / (sv - pk.f[1]);
    if (lane == 0) { ub[i] = ui; ub[j] = uj; }
    const f32x2 uui = (f32x2){ui, ui};
    const f32x2 uuj = (f32x2){uj, uj};
#pragma unroll
    for (int e2 = 0; e2 < 4; ++e2) {
      caA[e2] = pkfma(uui, d2a[e2], caA[e2]);
      caA[e2] = pkfma(uuj, d2c[e2], caA[e2]);
      caB[e2] = pkfma(uui, d2b[e2], caB[e2]);
    }
  }

  __shared__ float cred[4][1024];
  const float* fA = (const float*)caA;
  const float* fB = (const float*)caB;
#pragma unroll
  for (int e = 0; e < 8; ++e) {
    cred[w][e * 64 + lane] = fA[e];
    cred[w][(8 + e) * 64 + lane] = fB[e];
  }
  __syncthreads();
  float* cp = colpart + (((size_t)blk * 48 + bh) << 10);
#pragma unroll
  for (int q = 0; q < 4; ++q) {
    int p = tid + q * 256;
    cp[p] = cred[0][p] + cred[1][p] + cred[2][p] + cred[3][p];
  }
}

// ------ finish v-update: v_j = MU/(su - colsum_j). nst = colpart depth --------------
__global__ __launch_bounds__(256) void vfin_k(
    const float* __restrict__ colpart, const float* __restrict__ u,
    float* __restrict__ vv, int nst) {
  const int cq = blockIdx.x, bh = blockIdx.y;
  const int tid = threadIdx.x;
  float su = 0.f;
  for (int t = tid; t < 1024; t += 256) su += u[(bh << 10) + t];
#pragma unroll
  for (int o = 1; o < 64; o <<= 1) su += __shfl_xor(su, o);
  __shared__ float red[4];
  if ((tid & 63) == 0) red[tid >> 6] = su;
  __syncthreads();
  su = red[0] + red[1] + red[2] + red[3];
  const int c = cq * 256 + tid;
  const int p = permcol(c);
  float s = 0.f;
  for (int st = 0; st < nst; ++st)
    s += colpart[(((size_t)st * 48 + bh) << 10) + p];
  vv[(bh << 10) + c] = MU / (su - s);
}

// ---------------- V' = v ⊙ V (bf16, d-major) + Wd[bh][d] = sum_t V'[t][d] -----------
__global__ __launch_bounds__(256) void vprep_k(const float* __restrict__ Vt,
                                               const float* __restrict__ vv,
                                               ushort* __restrict__ Vpt,
                                               float* __restrict__ Wd) {
  const int bd = blockIdx.x;
  const int bh = bd >> 6;
  const int tid = threadIdx.x;
  const float* src = Vt + ((size_t)bd << 10);
  const float* vb = vv + (bh << 10);
  ushort* dst = Vpt + ((size_t)bd << 10);
  float s = 0.f;
  for (int t = tid; t < 1024; t += 256) {
    float p = src[t] * vb[t];
    s += p;
    dst[t] = f2bf(p);
  }
  for (int o = 32; o; o >>= 1) s += __shfl_down(s, o);
  __shared__ float red[4];
  if ((tid & 63) == 0) red[tid >> 6] = s;
  __syncthreads();
  if (tid == 0) Wd[bd] = red[0] + red[1] + red[2] + red[3];
}

// ------- y = 1024*u ⊙ (Wd - D @ V'), heavy q-tiles first (triangular K) -------------
__global__ __launch_bounds__(256) void gemm_pv_k(
    const ushort* __restrict__ SK, const ushort* __restrict__ Vpt,
    const float* __restrict__ u, const float* __restrict__ Wd,
    ushort* __restrict__ yb) {
  const int qt = 15 - blockIdx.y, bh = blockIdx.z;
  const int arow0 = qt * 64;
  const int brow0 = 0;
  const int kdim = (qt + 1) << 6;
  const ushort* A = SK + ((size_t)bh << 20);
  const ushort* B = Vpt + ((size_t)bh << 16);
  GEMM_PROLOG();
  GEMM_LOOP(A, B, 1024, 1024, kdim);
  const int bb = bh / 12, h = bh - bb * 12;
  GEMM_EPILOG({
    float yv = (Wd[(bh << 6) + gc] - val) * u[(bh << 10) + gr] * 1024.0f;
    yb[((size_t)((bb << 10) + gr)) * 768 + (h << 6) + gc] = f2bf(yv);
  });
}

// ------------------------------------------------------------------------------------
extern "C" void kernel_launch(void* const* d_in, const int* in_sizes, int n_in,
                              void* d_out, int out_size, void* d_ws, size_t ws_size,
                              hipStream_t stream) {
  const float* x      = (const float*)d_in[0];
  const float* ln_w   = (const float*)d_in[1];
  const float* ln_b   = (const float*)d_in[2];
  const float* W_attn = (const float*)d_in[3];
  const float* b_attn = (const float*)d_in[4];
  const float* W_proj = (const float*)d_in[5];
  const float* b_proj = (const float*)d_in[6];
  float* out = (float*)d_out;
  char* ws = (char*)d_ws;

  // ws layout (bytes); peak use ~144 MB
  ushort* xnb = (ushort*)(ws + 0);            // 4096*832 bf16 (dead after gemm_qkv)
  ushort* WaT = (ushort*)(ws + 6815744);      // 2304*832 bf16
  ushort* WpT = (ushort*)(ws + 10649600);     // 768*768 bf16
  ushort* qb  = (ushort*)(ws + 11829248);     // 48*1024*64 bf16 (dead after gemm_s)
  ushort* kb  = (ushort*)(ws + 18120704);     // 48*1024*64 bf16 (dead after gemm_s)
  float*  Vt  = (float*) (ws + 24412160);     // 48*64*1024 f32 (dead after vprep)
  ushort* SK  = (ushort*)(ws + 36995072);     // 48*1024*1024 bf16 (S, then D)
  ushort* Vpt = (ushort*)(ws + 137658368);    // 48*64*1024 bf16
  // overlays:
  float*  colpart = (float*)(ws + 11829248);  // 64*48*1024 f32 on dead qb/kb
  ushort* yb  = (ushort*)(ws + 24412160);     // 4096*768 bf16 on dead Vt
  float*  u   = (float*) (ws + 0);            // 48*1024 f32 on dead xnb
  float*  vv  = (float*) (ws + 196608);       //   "
  float*  Wd  = (float*) (ws + 393216);       //   "

  hipLaunchKernelGGL(ln_k, dim3(4096), dim3(256), 0, stream, x, ln_w, ln_b, xnb);
  hipLaunchKernelGGL(tr_k, dim3(72, 26), dim3(256), 0, stream, W_attn, WaT, 769, 2304, 832);
  hipLaunchKernelGGL(tr_k, dim3(24, 24), dim3(256), 0, stream, W_proj, WpT, 768, 768, 768);
  hipLaunchKernelGGL(gemm_qkv_k, dim3(18, 32), dim3(256), 0, stream,
                     xnb, WaT, b_attn, qb, kb, Vt);
  hipLaunchKernelGGL(gemm_s_k, dim3(16, 16, 48), dim3(256), 0, stream, qb, kb, SK);
  hipLaunchKernelGGL(kmat_k, dim3(32, 48), dim3(256), 0, stream, SK, u, colpart);
  hipLaunchKernelGGL(vfin_k, dim3(4, 48), dim3(256), 0, stream, colpart, u, vv, 64);
  for (int it = 0; it < 5; ++it) {
    hipLaunchKernelGGL(sink_k, dim3(16, 48), dim3(256), 0, stream, SK, vv, u, colpart);
    hipLaunchKernelGGL(vfin_k, dim3(4, 48), dim3(256), 0, stream, colpart, u, vv, 16);
  }
  hipLaunchKernelGGL(vprep_k, dim3(3072), dim3(256), 0, stream, Vt, vv, Vpt, Wd);
  hipLaunchKernelGGL(gemm_pv_k, dim3(1, 16, 48), dim3(256), 0, stream, SK, Vpt, u, Wd, yb);
  hipLaunchKernelGGL(gemm_proj_k, dim3(6, 32), dim3(256), 0, stream, yb, WpT, b_proj, out);
}